// Round 3
// baseline (1042.798 us; speedup 1.0000x reference)
//
#include <hip/hip_runtime.h>

typedef unsigned short u16;
typedef __attribute__((ext_vector_type(8))) short bf16x8;
typedef __attribute__((ext_vector_type(4))) float f32x4;

#define NV 50257
#define NVP 50304
#define NR 960          // 60*16 rows
#define NCB 786         // 50304/64 col blocks

__device__ __forceinline__ u16 f2b(float x) {
    union { float f; unsigned u; } v; v.f = x;
    unsigned r = v.u + 0x7FFFu + ((v.u >> 16) & 1u);
    return (u16)(r >> 16);
}
__device__ __forceinline__ float b2f(u16 h) {
    union { unsigned u; float f; } v; v.u = ((unsigned)h) << 16;
    return v.f;
}
__device__ __forceinline__ float sigm(float x) { return 1.f / (1.f + __expf(-x)); }

__device__ __forceinline__ void gload16(const u16* g, u16* l) {
    __builtin_amdgcn_global_load_lds((const __attribute__((address_space(1))) void*)g,
                                     (__attribute__((address_space(3))) void*)l, 16, 0, 0);
}

// ---------------- prep kernels ----------------
__global__ void conv_k(const float* __restrict__ in, u16* __restrict__ out, int n) {
    int i = blockIdx.x * 256 + threadIdx.x;
    if (i < n) out[i] = f2b(in[i]);
}
__global__ void embpad_k(const float* __restrict__ W_emb, u16* __restrict__ out) {
    int i = blockIdx.x * 256 + threadIdx.x;
    if (i < NVP * 128) out[i] = (i < NV * 128) ? f2b(W_emb[i]) : (u16)0;
}
__global__ void attnT_k(const float* __restrict__ We, const float* __restrict__ Wd, u16* __restrict__ out) {
    int i = blockIdx.x * 256 + threadIdx.x;
    if (i < 1024 * 512) {
        int n = i >> 9, k = i & 511;
        float v = (n < 512) ? We[k * 512 + n] : Wd[k * 512 + (n - 512)];
        out[i] = f2b(v);
    }
}
__global__ void projT_k(const float* __restrict__ Wp, u16* __restrict__ out) {
    int i = blockIdx.x * 256 + threadIdx.x;
    if (i < 1536 * 128) {
        int k = i >> 7, e = i & 127;
        out[i] = f2b(Wp[e * 1536 + k]);
    }
}
__global__ void gather_k(const float* __restrict__ W_emb, const int* __restrict__ tgt, u16* __restrict__ out) {
    int i = blockIdx.x * 256 + threadIdx.x;
    if (i < NR * 128) {
        int r = i >> 7, e = i & 127;
        out[i] = f2b(W_emb[(size_t)tgt[r] * 128 + e]);
    }
}
__global__ void init_k(const float* __restrict__ c0, const float* __restrict__ h0,
                       u16* __restrict__ hb0) {
    int i = blockIdx.x * 256 + threadIdx.x;
    if (i < 8192) { hb0[i] = f2b(h0[i]); }
    (void)c0;
}

// h_e [s][b][512] f32 -> h_eB [b][448][512] bf16 (pad s zero), h_eT [b][512][448] bf16
__global__ __launch_bounds__(256) void prep_he_k(const float* __restrict__ h_e,
                                                 u16* __restrict__ h_eB, u16* __restrict__ h_eT) {
    __shared__ u16 tile[64][68];
    const int st = blockIdx.x, b = blockIdx.y, tid = threadIdx.x;
    for (int dc = 0; dc < 8; dc++) {
        const int d0 = dc * 64;
#pragma unroll
        for (int k = 0; k < 4; k++) {
            int o = k * 256 + tid;
            int si = o >> 4, d4 = (o & 15) * 4;
            int s = st * 64 + si;
            float4 f = make_float4(0.f, 0.f, 0.f, 0.f);
            if (s < 400) f = *(const float4*)&h_e[((size_t)s * 16 + b) * 512 + d0 + d4];
            tile[si][d4 + 0] = f2b(f.x); tile[si][d4 + 1] = f2b(f.y);
            tile[si][d4 + 2] = f2b(f.z); tile[si][d4 + 3] = f2b(f.w);
        }
        __syncthreads();
#pragma unroll
        for (int k = 0; k < 4; k++) {
            int o = k * 256 + tid;
            int si = o >> 4, d4 = (o & 15) * 4;
            ushort4 u; u.x = tile[si][d4]; u.y = tile[si][d4 + 1]; u.z = tile[si][d4 + 2]; u.w = tile[si][d4 + 3];
            *(ushort4*)&h_eB[((size_t)b * 448 + st * 64 + si) * 512 + d0 + d4] = u;
        }
#pragma unroll
        for (int k = 0; k < 4; k++) {
            int o = k * 256 + tid;
            int di = o >> 4, s4 = (o & 15) * 4;
            ushort4 u; u.x = tile[s4][di]; u.y = tile[s4 + 1][di]; u.z = tile[s4 + 2][di]; u.w = tile[s4 + 3][di];
            *(ushort4*)&h_eT[((size_t)b * 512 + d0 + di) * 448 + st * 64 + s4] = u;
        }
        __syncthreads();
    }
}

// hd [(u*16+b)][512] f32 -> hdUB [b][64][512] bf16 (pad u zero), hdT [b][512][64] bf16
__global__ __launch_bounds__(256) void prep_hd_k(const float* __restrict__ hd,
                                                 u16* __restrict__ hdUB, u16* __restrict__ hdT) {
    __shared__ u16 tile[64][68];
    const int b = blockIdx.x, tid = threadIdx.x;
    for (int dc = 0; dc < 8; dc++) {
        const int d0 = dc * 64;
#pragma unroll
        for (int k = 0; k < 4; k++) {
            int o = k * 256 + tid;
            int ui = o >> 4, d4 = (o & 15) * 4;
            float4 f = make_float4(0.f, 0.f, 0.f, 0.f);
            if (ui < 60) f = *(const float4*)&hd[((size_t)ui * 16 + b) * 512 + d0 + d4];
            tile[ui][d4 + 0] = f2b(f.x); tile[ui][d4 + 1] = f2b(f.y);
            tile[ui][d4 + 2] = f2b(f.z); tile[ui][d4 + 3] = f2b(f.w);
        }
        __syncthreads();
#pragma unroll
        for (int k = 0; k < 4; k++) {
            int o = k * 256 + tid;
            int ui = o >> 4, d4 = (o & 15) * 4;
            ushort4 u; u.x = tile[ui][d4]; u.y = tile[ui][d4 + 1]; u.z = tile[ui][d4 + 2]; u.w = tile[ui][d4 + 3];
            *(ushort4*)&hdUB[((size_t)b * 64 + ui) * 512 + d0 + d4] = u;
        }
#pragma unroll
        for (int k = 0; k < 4; k++) {
            int o = k * 256 + tid;
            int di = o >> 4, u4 = (o & 15) * 4;
            ushort4 u; u.x = tile[u4][di]; u.y = tile[u4 + 1][di]; u.z = tile[u4 + 2][di]; u.w = tile[u4 + 3][di];
            *(ushort4*)&hdT[((size_t)b * 512 + d0 + di) * 64 + u4] = u;
        }
        __syncthreads();
    }
}

// q [(t*16+b)][1024] f32 -> qeB [b][64][512], qdB [b][64][512] bf16 (pad t zero)
__global__ void qprep_k(const float* __restrict__ q, u16* __restrict__ qeB, u16* __restrict__ qdB) {
    const int t = blockIdx.x, b = blockIdx.y, tid = threadIdx.x;
    const int o = tid * 4;
    float4 f = make_float4(0.f, 0.f, 0.f, 0.f);
    if (t < 60) f = *(const float4*)&q[((size_t)t * 16 + b) * 1024 + o];
    ushort4 u; u.x = f2b(f.x); u.y = f2b(f.y); u.z = f2b(f.z); u.w = f2b(f.w);
    if (o < 512) *(ushort4*)&qeB[((size_t)b * 64 + t) * 512 + o] = u;
    else         *(ushort4*)&qdB[((size_t)b * 64 + t) * 512 + (o - 512)] = u;
}

// ---------------- 64x64 bf16 MFMA GEMM, f32 out (small mats) ----------------
__global__ __launch_bounds__(256) void gemm64_k(
    const u16* __restrict__ A, const u16* __restrict__ Bm,
    int K, int ldC, float* __restrict__ outF,
    const float* __restrict__ bias1, const float* __restrict__ bias2)
{
    __shared__ u16 Al[64 * 40];
    __shared__ u16 Bl[64 * 40];
    const int tid = threadIdx.x;
    const int wv = tid >> 6, ln = tid & 63;
    const int bn = blockIdx.x, bm = blockIdx.y;
    const int srow = tid >> 2;
    const int skc = (tid & 3) * 8;
    const size_t aoff = (size_t)(bm * 64 + srow) * K + skc;
    const size_t boff = (size_t)(bn * 64 + srow) * K + skc;
    f32x4 acc[4];
#pragma unroll
    for (int t = 0; t < 4; t++) acc[t] = (f32x4){0.f, 0.f, 0.f, 0.f};
    const int fra = (wv * 16 + (ln & 15)) * 40 + (ln >> 4) * 8;
    for (int kb = 0; kb < K; kb += 32) {
        *(bf16x8*)&Al[srow * 40 + skc] = *(const bf16x8*)&A[aoff + kb];
        *(bf16x8*)&Bl[srow * 40 + skc] = *(const bf16x8*)&Bm[boff + kb];
        __syncthreads();
        bf16x8 af = *(const bf16x8*)&Al[fra];
#pragma unroll
        for (int t = 0; t < 4; t++) {
            bf16x8 bfr = *(const bf16x8*)&Bl[(t * 16 + (ln & 15)) * 40 + (ln >> 4) * 8];
            acc[t] = __builtin_amdgcn_mfma_f32_16x16x32_bf16(af, bfr, acc[t], 0, 0, 0);
        }
        __syncthreads();
    }
    const int rl = wv * 16 + (ln >> 4) * 4;
    const int cl = (ln & 15);
#pragma unroll
    for (int t = 0; t < 4; t++) {
        int col = bn * 64 + t * 16 + cl;
        float bv = 0.f;
        if (bias1) bv += bias1[col];
        if (bias2) bv += bias2[col];
#pragma unroll
        for (int r = 0; r < 4; r++)
            outF[(size_t)(bm * 64 + rl + r) * ldC + col] = acc[t][r] + bv;
    }
}

// ---------------- batched 64-wide A*B^T GEMM (M=64), f32 out ----------------
__global__ __launch_bounds__(256) void gemm_b_k(
    const u16* __restrict__ A, long sA,
    const u16* __restrict__ Bm, long sB, int K,
    float* __restrict__ C, long sC, int ldC)
{
    __shared__ u16 Al[64 * 40];
    __shared__ u16 Bl[64 * 40];
    const int tid = threadIdx.x;
    const int wv = tid >> 6, ln = tid & 63;
    const int bn = blockIdx.x, bz = blockIdx.z;
    A += (size_t)bz * sA; Bm += (size_t)bz * sB; C += (size_t)bz * sC;
    const int srow = tid >> 2;
    const int skc = (tid & 3) * 8;
    const size_t aoff = (size_t)srow * K + skc;
    const size_t boff = (size_t)(bn * 64 + srow) * K + skc;
    f32x4 acc[4];
#pragma unroll
    for (int t = 0; t < 4; t++) acc[t] = (f32x4){0.f, 0.f, 0.f, 0.f};
    const int fra = (wv * 16 + (ln & 15)) * 40 + (ln >> 4) * 8;
    for (int kb = 0; kb < K; kb += 32) {
        *(bf16x8*)&Al[srow * 40 + skc] = *(const bf16x8*)&A[aoff + kb];
        *(bf16x8*)&Bl[srow * 40 + skc] = *(const bf16x8*)&Bm[boff + kb];
        __syncthreads();
        bf16x8 af = *(const bf16x8*)&Al[fra];
#pragma unroll
        for (int t = 0; t < 4; t++) {
            bf16x8 bfr = *(const bf16x8*)&Bl[(t * 16 + (ln & 15)) * 40 + (ln >> 4) * 8];
            acc[t] = __builtin_amdgcn_mfma_f32_16x16x32_bf16(af, bfr, acc[t], 0, 0, 0);
        }
        __syncthreads();
    }
    const int rl = wv * 16 + (ln >> 4) * 4;
    const int cl = (ln & 15);
#pragma unroll
    for (int t = 0; t < 4; t++) {
        int col = bn * 64 + t * 16 + cl;
#pragma unroll
        for (int r = 0; r < 4; r++)
            C[(size_t)(rl + r) * ldC + col] = acc[t][r];
    }
}

// ---------------- 128x128 m97-style GEMM: MODE1 tanh->bf16, MODE2 streaming LSE + targ ----------------
template<int MODE>
__global__ __launch_bounds__(256) void gemm128_k(
    const u16* __restrict__ A, const u16* __restrict__ Bm, const int K,
    u16* __restrict__ outB, const int ldO,
    const float* __restrict__ bias,
    float* __restrict__ pmax, float* __restrict__ psum, const int vc0,
    const int* __restrict__ tgt, float* __restrict__ lt)
{
    __shared__ u16 Al[128 * 32];
    __shared__ u16 Bl[128 * 32];
    const int tid = threadIdx.x;
    const int w = tid >> 6, ln = tid & 63;
    const int wr = w >> 1, wc = w & 1;
    const int bn = blockIdx.x, bm = blockIdx.y;
    const int srow = w * 16 + (ln >> 2);
    const int scol = (ln & 3) * 8;
    const u16* ag = A + (size_t)bm * 128 * K + (size_t)srow * K + scol;
    const u16* bg = Bm + (size_t)bn * 128 * K + (size_t)srow * K + scol;
    u16* la = &Al[w * 16 * 32];
    u16* lb = &Bl[w * 16 * 32];
    f32x4 acc[4][4];
#pragma unroll
    for (int m = 0; m < 4; m++)
#pragma unroll
        for (int n = 0; n < 4; n++) acc[m][n] = (f32x4){0.f, 0.f, 0.f, 0.f};
    const int ra = (wr * 64 + (ln & 15)) * 32 + (ln >> 4) * 8;
    const int rb = (wc * 64 + (ln & 15)) * 32 + (ln >> 4) * 8;

    for (int kb = 0; kb < K; kb += 32) {
        gload16(ag + kb, la);
        gload16(ag + (size_t)64 * K + kb, la + 64 * 32);
        gload16(bg + kb, lb);
        gload16(bg + (size_t)64 * K + kb, lb + 64 * 32);
        __syncthreads();
        bf16x8 af[4], bfr[4];
#pragma unroll
        for (int m = 0; m < 4; m++) af[m] = *(const bf16x8*)&Al[ra + m * 16 * 32];
#pragma unroll
        for (int n = 0; n < 4; n++) bfr[n] = *(const bf16x8*)&Bl[rb + n * 16 * 32];
#pragma unroll
        for (int m = 0; m < 4; m++)
#pragma unroll
            for (int n = 0; n < 4; n++)
                acc[m][n] = __builtin_amdgcn_mfma_f32_16x16x32_bf16(af[m], bfr[n], acc[m][n], 0, 0, 0);
        __syncthreads();
    }

    const int cl = ln & 15, rg = ln >> 4;
    if (MODE == 1) {
#pragma unroll
        for (int m = 0; m < 4; m++) {
            int row0 = bm * 128 + wr * 64 + m * 16 + rg * 4;
#pragma unroll
            for (int n = 0; n < 4; n++) {
                int col = bn * 128 + wc * 64 + n * 16 + cl;
#pragma unroll
                for (int r = 0; r < 4; r++)
                    outB[(size_t)(row0 + r) * ldO + col] = f2b(tanhf(acc[m][n][r]));
            }
        }
    } else {
        const int cbg = (vc0 >> 6) + bn * 2 + wc;
        float bo[4]; int vg[4];
#pragma unroll
        for (int n = 0; n < 4; n++) {
            vg[n] = vc0 + bn * 128 + wc * 64 + n * 16 + cl;
            bo[n] = (vg[n] < NV) ? bias[vg[n]] : 0.f;
        }
#pragma unroll
        for (int m = 0; m < 4; m++) {
            int row0 = bm * 128 + wr * 64 + m * 16 + rg * 4;
#pragma unroll
            for (int r = 0; r < 4; r++) {
                int row = row0 + r;
                int tv = (row < NR) ? tgt[row] : -1;
                float lg[4]; float mm = -1e30f;
#pragma unroll
                for (int n = 0; n < 4; n++) {
                    lg[n] = (vg[n] < NV) ? (acc[m][n][r] + bo[n]) : -1e30f;
                    mm = fmaxf(mm, lg[n]);
                    if (vg[n] == tv) lt[row] = lg[n];
                }
                mm = fmaxf(mm, __shfl_xor(mm, 1, 64));
                mm = fmaxf(mm, __shfl_xor(mm, 2, 64));
                mm = fmaxf(mm, __shfl_xor(mm, 4, 64));
                mm = fmaxf(mm, __shfl_xor(mm, 8, 64));
                float s = 0.f;
#pragma unroll
                for (int n = 0; n < 4; n++) s += __expf(lg[n] - mm);
                s += __shfl_xor(s, 1, 64); s += __shfl_xor(s, 2, 64);
                s += __shfl_xor(s, 4, 64); s += __shfl_xor(s, 8, 64);
                if (cl == 0 && row < NR) {
                    pmax[(size_t)cbg * NR + row] = mm;
                    psum[(size_t)cbg * NR + row] = s;
                }
            }
        }
    }
}

// ---------------- persistent LSTM: all 60 steps, 32 blocks, device barrier ----------------
__global__ __launch_bounds__(256) void lstm_all(
    const u16* __restrict__ WhhB, u16* __restrict__ hB,
    const float* __restrict__ preGI, const float* __restrict__ c0,
    float* __restrict__ hd, u16* __restrict__ hdB, unsigned* __restrict__ bar)
{
    __shared__ float gl[1024];
    const int tid = threadIdx.x;
    const int g = tid >> 6, ln = tid & 63;
    const int dt = blockIdx.x;
    const int arow = (g * 512 + dt * 16 + (ln & 15)) * 512 + ((ln >> 4) * 8);
    const int brow = (ln & 15) * 512 + ((ln >> 4) * 8);
    // W_hh rows for this block stay in registers across all 60 steps
    bf16x8 aw[16];
#pragma unroll
    for (int kb = 0; kb < 16; kb++) aw[kb] = *(const bf16x8*)&WhhB[arow + kb * 32];
    const int b = tid >> 4, dl = tid & 15;
    const int d = dt * 16 + dl;
    float c = c0[b * 512 + d];

    for (int t = 0; t < 60; t++) {
        const u16* hin = hB + (size_t)(t & 1) * 8192;
        f32x4 acc = {0.f, 0.f, 0.f, 0.f};
#pragma unroll
        for (int kb = 0; kb < 16; kb++) {
            bf16x8 bv = *(const bf16x8*)&hin[brow + kb * 32];
            acc = __builtin_amdgcn_mfma_f32_16x16x32_bf16(aw[kb], bv, acc, 0, 0, 0);
        }
#pragma unroll
        for (int r = 0; r < 4; r++)
            gl[g * 256 + ((ln >> 4) * 4 + r) * 16 + (ln & 15)] = acc[r];
        __syncthreads();
        const float* pg = preGI + (size_t)t * 16 * 2048;
        float gi = gl[0 * 256 + dl * 16 + b] + pg[b * 2048 + 0 * 512 + d];
        float gf = gl[1 * 256 + dl * 16 + b] + pg[b * 2048 + 1 * 512 + d];
        float gg = gl[2 * 256 + dl * 16 + b] + pg[b * 2048 + 2 * 512 + d];
        float go = gl[3 * 256 + dl * 16 + b] + pg[b * 2048 + 3 * 512 + d];
        c = sigm(gf) * c + sigm(gi) * tanhf(gg);
        float h = sigm(go) * tanhf(c);
        hd[(size_t)t * 8192 + b * 512 + d] = h;
        u16 hb = f2b(h);
        hdB[(size_t)t * 8192 + b * 512 + d] = hb;
        hB[(size_t)((t & 1) ^ 1) * 8192 + b * 512 + d] = hb;
        // device barrier across 32 blocks
        __threadfence();
        __syncthreads();
        if (tid == 0) {
            __hip_atomic_fetch_add(bar, 1u, __ATOMIC_RELEASE, __HIP_MEMORY_SCOPE_AGENT);
            const unsigned target = 32u * (unsigned)(t + 1);
            while (__hip_atomic_load(bar, __ATOMIC_ACQUIRE, __HIP_MEMORY_SCOPE_AGENT) < target) {
                __builtin_amdgcn_s_sleep(8);
            }
        }
        __syncthreads();
    }
}

// ---------------- softmax kernels ----------------
__global__ __launch_bounds__(256) void softmax_e_k(
    const float* __restrict__ Se, const float* __restrict__ algn,
    u16* __restrict__ PeB, float* __restrict__ copysum)
{
    const int wid = blockIdx.x * 4 + (threadIdx.x >> 6);
    const int l = threadIdx.x & 63;
    const int t = wid >> 4, b = wid & 15;
    const float* srow = &Se[((size_t)b * 64 + t) * 448];
    float v[7];
    float m = -1e30f;
#pragma unroll
    for (int i = 0; i < 7; i++) {
        int s = l + i * 64;
        v[i] = (s < 400) ? srow[s] : -1e30f;
        m = fmaxf(m, v[i]);
    }
#pragma unroll
    for (int mk = 1; mk < 64; mk <<= 1) m = fmaxf(m, __shfl_xor(m, mk, 64));
    const float* arow = &algn[((size_t)t * 16 + b) * 400];
    float se = 0.f, ca = 0.f;
#pragma unroll
    for (int i = 0; i < 7; i++) {
        int s = l + i * 64;
        float e = (s < 400) ? __expf(v[i] - m) : 0.f;
        v[i] = e; se += e;
        if (s < 400) ca += e * arow[s];
    }
#pragma unroll
    for (int mk = 1; mk < 64; mk <<= 1) { se += __shfl_xor(se, mk, 64); ca += __shfl_xor(ca, mk, 64); }
    float inv = 1.f / se;
#pragma unroll
    for (int i = 0; i < 7; i++) {
        int s = l + i * 64;
        PeB[((size_t)b * 64 + t) * 448 + s] = f2b(v[i] * inv);
    }
    if (l == 0) copysum[t * 16 + b] = ca * inv;
}

__global__ __launch_bounds__(256) void softmax_d_k(const float* __restrict__ Sd, u16* __restrict__ PdB)
{
    const int wid = blockIdx.x * 4 + (threadIdx.x >> 6);
    const int l = threadIdx.x & 63;
    const int t = wid >> 4, b = wid & 15;
    float v = Sd[((size_t)b * 64 + t) * 64 + l];
    bool ok = (l <= t) && (l < 60);
    v = ok ? v : -1e30f;
    float m = v;
#pragma unroll
    for (int mk = 1; mk < 64; mk <<= 1) m = fmaxf(m, __shfl_xor(m, mk, 64));
    float e = ok ? __expf(v - m) : 0.f;
    float se = e;
#pragma unroll
    for (int mk = 1; mk < 64; mk <<= 1) se += __shfl_xor(se, mk, 64);
    float p = (t == 0) ? 0.f : e / se;
    PdB[((size_t)b * 64 + t) * 64 + l] = f2b(p);
}

// ---------------- cat assembly + p_switch ----------------
__global__ __launch_bounds__(256) void cat_k(
    const float* __restrict__ hd, const float* __restrict__ ce2, const float* __restrict__ cd2,
    const float* __restrict__ W_u, const float* __restrict__ b_u,
    u16* __restrict__ catB, float* __restrict__ p_switch)
{
    const int r = blockIdx.x, tid = threadIdx.x;
    if (r >= NR) {
        for (int j = tid; j < 1536; j += 256) catB[(size_t)r * 1536 + j] = 0;
        return;
    }
    const int t = r >> 4, b = r & 15;
    float partial = 0.f;
    for (int j = tid; j < 1536; j += 256) {
        float v;
        if (j < 512) v = hd[(size_t)r * 512 + j];
        else if (j < 1024) v = ce2[((size_t)b * 64 + t) * 512 + (j - 512)];
        else v = cd2[((size_t)b * 64 + t) * 512 + (j - 1024)];
        catB[(size_t)r * 1536 + j] = f2b(v);
        partial += v * W_u[j];
    }
#pragma unroll
    for (int mk = 1; mk < 64; mk <<= 1) partial += __shfl_xor(partial, mk, 64);
    __shared__ float red[4];
    if ((tid & 63) == 0) red[tid >> 6] = partial;
    __syncthreads();
    if (tid == 0) {
        float u = red[0] + red[1] + red[2] + red[3] + b_u[0];
        p_switch[r] = 1.f / (1.f + __expf(-u));
    }
}

// ---------------- per-row LSE combine (wave per row) ----------------
__global__ __launch_bounds__(256) void rowred_k(
    const float* __restrict__ pmax, const float* __restrict__ psum,
    const float* __restrict__ lt, const float* __restrict__ p_switch,
    const float* __restrict__ copysum, const int* __restrict__ tgt,
    float* __restrict__ terms)
{
    const int r = blockIdx.x * 4 + (threadIdx.x >> 6);
    const int l = threadIdx.x & 63;
    float m = -1e30f, s = 0.f;
    for (int cb = l; cb < NCB; cb += 64) {
        float me = pmax[(size_t)cb * NR + r];
        float se = psum[(size_t)cb * NR + r];
        float M2 = fmaxf(m, me);
        s = s * __expf(m - M2) + se * __expf(me - M2);
        m = M2;
    }
#pragma unroll
    for (int mk = 1; mk < 64; mk <<= 1) {
        float mo = __shfl_xor(m, mk, 64);
        float so = __shfl_xor(s, mk, 64);
        float M2 = fmaxf(m, mo);
        s = s * __expf(m - M2) + so * __expf(mo - M2);
        m = M2;
    }
    if (l == 0) {
        float ps = p_switch[r];
        float tg = (1.f - ps) * __expf(lt[r] - m) / s;
        float tc = ps * copysum[r];
        terms[r] = (tgt[r] != 0) ? -logf(tg + tc + 2e-12f) : 0.f;
    }
}

__global__ __launch_bounds__(256) void final_k(const float* __restrict__ terms, float* __restrict__ out)
{
    const int tid = threadIdx.x;
    float p = 0.f;
    for (int i = tid; i < NR; i += 256) p += terms[i];
#pragma unroll
    for (int mk = 1; mk < 64; mk <<= 1) p += __shfl_xor(p, mk, 64);
    __shared__ float red[4];
    if ((tid & 63) == 0) red[tid >> 6] = p;
    __syncthreads();
    if (tid == 0) out[0] = red[0] + red[1] + red[2] + red[3];
}

// ---------------- host launch ----------------
extern "C" void kernel_launch(void* const* d_in, const int* in_sizes, int n_in,
                              void* d_out, int out_size, void* d_ws, size_t ws_size,
                              hipStream_t stream)
{
    const int*   tgt    = (const int*)d_in[0];
    const float* algn   = (const float*)d_in[2];
    const float* h_e    = (const float*)d_in[3];
    const float* h0     = (const float*)d_in[4];
    const float* c0     = (const float*)d_in[5];
    const float* W_emb  = (const float*)d_in[6];
    const float* W_ih   = (const float*)d_in[7];
    const float* W_hh   = (const float*)d_in[8];
    const float* b_ih   = (const float*)d_in[9];
    const float* b_hh   = (const float*)d_in[10];
    const float* W_ae   = (const float*)d_in[11];
    const float* W_ad   = (const float*)d_in[12];
    const float* W_proj = (const float*)d_in[13];
    const float* W_u    = (const float*)d_in[14];
    const float* b_u    = (const float*)d_in[15];
    const float* b_out  = (const float*)d_in[16];
    (void)in_sizes; (void)n_in; (void)out_size; (void)ws_size;

    char* ws = (char*)d_ws;
    size_t off = 0;
    auto alloc = [&](size_t bytes) -> char* {
        char* p = ws + off;
        off += (bytes + 255) & ~(size_t)255;
        return p;
    };
    u16* wbuf    = (u16*)alloc((size_t)12800 * 1536 * 2);   // also overlaid: attention scratch
    u16* catB    = (u16*)alloc((size_t)1024 * 1536 * 2);
    u16* WprojT  = (u16*)alloc((size_t)1536 * 128 * 2);
    u16* WihB    = (u16*)alloc((size_t)2048 * 128 * 2);
    u16* WhhB    = (u16*)alloc((size_t)2048 * 512 * 2);
    u16* WattnT  = (u16*)alloc((size_t)1024 * 512 * 2);
    u16* WembB   = (u16*)alloc((size_t)NVP * 128 * 2);
    u16* embB    = (u16*)alloc((size_t)NR * 128 * 2);
    u16* hdB     = (u16*)alloc((size_t)NR * 512 * 2);
    u16* hB      = (u16*)alloc((size_t)2 * 8192 * 2);
    float* preGI = (float*)alloc((size_t)NR * 2048 * 4);
    float* hd    = (float*)alloc((size_t)NR * 512 * 4);
    float* q     = (float*)alloc((size_t)NR * 1024 * 4);
    float* p_sw  = (float*)alloc(NR * 4);
    float* copys = (float*)alloc(NR * 4);
    float* lt    = (float*)alloc(NR * 4);
    float* terms = (float*)alloc(NR * 4);
    float* pmax  = (float*)alloc((size_t)NCB * NR * 4);
    float* psum  = (float*)alloc((size_t)NCB * NR * 4);
    unsigned* bar = (unsigned*)alloc(256);

    // attention scratch overlaid into wbuf (wbuf used only after cat_k)
    u16* h_eB = wbuf;                      // 16*448*512
    u16* h_eT = h_eB + (size_t)16 * 448 * 512;
    u16* qeB  = h_eT + (size_t)16 * 448 * 512;  // 16*64*512
    u16* qdB  = qeB + (size_t)16 * 64 * 512;
    u16* hdUB = qdB + (size_t)16 * 64 * 512;
    u16* hdT  = hdUB + (size_t)16 * 64 * 512;
    u16* PeB  = hdT + (size_t)16 * 64 * 512;    // 16*64*448
    u16* PdB  = PeB + (size_t)16 * 64 * 448;    // 16*64*64
    float* Se = (float*)(PdB + (size_t)16 * 64 * 64);   // 16*64*448 f32
    float* Sd = Se + (size_t)16 * 64 * 448;             // 16*64*64
    float* ce2 = Sd + (size_t)16 * 64 * 64;             // 16*64*512
    float* cd2 = ce2 + (size_t)16 * 64 * 512;           // 16*64*512

    // prep
    conv_k<<<dim3((2048 * 128 + 255) / 256), 256, 0, stream>>>(W_ih, WihB, 2048 * 128);
    conv_k<<<dim3((2048 * 512 + 255) / 256), 256, 0, stream>>>(W_hh, WhhB, 2048 * 512);
    embpad_k<<<dim3((NVP * 128 + 255) / 256), 256, 0, stream>>>(W_emb, WembB);
    attnT_k<<<dim3((1024 * 512 + 255) / 256), 256, 0, stream>>>(W_ae, W_ad, WattnT);
    projT_k<<<dim3((1536 * 128 + 255) / 256), 256, 0, stream>>>(W_proj, WprojT);
    gather_k<<<dim3((NR * 128 + 255) / 256), 256, 0, stream>>>(W_emb, tgt, embB);
    init_k<<<dim3(32), 256, 0, stream>>>(c0, h0, hB);
    prep_he_k<<<dim3(7, 16), 256, 0, stream>>>(h_e, h_eB, h_eT);

    // preGI = emb @ W_ih^T + b_ih + b_hh
    gemm64_k<<<dim3(2048 / 64, NR / 64), 256, 0, stream>>>(embB, WihB, 128, 2048, preGI, b_ih, b_hh);

    // LSTM: all 60 steps in one persistent kernel with device barrier
    hipMemsetAsync(bar, 0, 4, stream);
    lstm_all<<<dim3(32), 256, 0, stream>>>(WhhB, hB, preGI, c0, hd, hdB, bar);

    // q = hd @ [W_attn_e | W_attn_d]
    gemm64_k<<<dim3(1024 / 64, NR / 64), 256, 0, stream>>>(hdB, WattnT, 512, 1024, q, nullptr, nullptr);
    qprep_k<<<dim3(64, 16), 256, 0, stream>>>(q, qeB, qdB);
    prep_hd_k<<<dim3(16), 256, 0, stream>>>(hd, hdUB, hdT);

    // scores
    gemm_b_k<<<dim3(7, 1, 16), 256, 0, stream>>>(qeB, 64 * 512, h_eB, 448 * 512, 512, Se, 64 * 448, 448);
    gemm_b_k<<<dim3(1, 1, 16), 256, 0, stream>>>(qdB, 64 * 512, hdUB, 64 * 512, 512, Sd, 64 * 64, 64);
    softmax_e_k<<<dim3(240), 256, 0, stream>>>(Se, algn, PeB, copys);
    softmax_d_k<<<dim3(240), 256, 0, stream>>>(Sd, PdB);
    // PV
    gemm_b_k<<<dim3(8, 1, 16), 256, 0, stream>>>(PeB, 64 * 448, h_eT, 512 * 448, 448, ce2, 64 * 512, 512);
    gemm_b_k<<<dim3(8, 1, 16), 256, 0, stream>>>(PdB, 64 * 64, hdT, 512 * 64, 64, cd2, 64 * 512, 512);

    cat_k<<<dim3(1024), 256, 0, stream>>>(hd, ce2, cd2, W_u, b_u, catB, p_sw);

    // chunked: W_out chunk = tanh(W_emb @ W_proj), then cat @ chunk^T with streaming LSE + targ capture
    const int vc0s[4] = {0, 12800, 25600, 38400};
    const int nccs[4] = {12800, 12800, 12800, 11904};
    for (int c = 0; c < 4; c++) {
        gemm128_k<1><<<dim3(1536 / 128, nccs[c] / 128), 256, 0, stream>>>(
            WembB + (size_t)vc0s[c] * 128, WprojT, 128, wbuf, 1536,
            nullptr, nullptr, nullptr, 0, nullptr, nullptr);
        gemm128_k<2><<<dim3(nccs[c] / 128, 1024 / 128), 256, 0, stream>>>(
            catB, wbuf, 1536, nullptr, 0, b_out, pmax, psum, vc0s[c], tgt, lt);
    }

    rowred_k<<<dim3(240), 256, 0, stream>>>(pmax, psum, lt, p_sw, copys, tgt, terms);
    final_k<<<dim3(1), 256, 0, stream>>>(terms, (float*)d_out);
}

// Round 4
// 851.163 us; speedup vs baseline: 1.2251x; 1.2251x over previous
//
#include <hip/hip_runtime.h>

typedef unsigned short u16;
typedef __attribute__((ext_vector_type(8))) short bf16x8;
typedef __attribute__((ext_vector_type(4))) float f32x4;
typedef __attribute__((ext_vector_type(4))) unsigned u32x4;

#define NV 50257
#define NVP 50304
#define NR 960          // 60*16 rows
#define NCB 786         // 50304/64 col blocks

__device__ __forceinline__ u16 f2b(float x) {
    union { float f; unsigned u; } v; v.f = x;
    unsigned r = v.u + 0x7FFFu + ((v.u >> 16) & 1u);
    return (u16)(r >> 16);
}
__device__ __forceinline__ float b2f(u16 h) {
    union { unsigned u; float f; } v; v.u = ((unsigned)h) << 16;
    return v.f;
}
__device__ __forceinline__ float sigm(float x) { return 1.f / (1.f + __expf(-x)); }

__device__ __forceinline__ void gload16(const u16* g, u16* l) {
    __builtin_amdgcn_global_load_lds((const __attribute__((address_space(1))) void*)g,
                                     (__attribute__((address_space(3))) void*)l, 16, 0, 0);
}

// ---- cross-XCD coherent (L2-bypass, Infinity-Cache coherence point) ops ----
__device__ __forceinline__ u32x4 cload16_async(const void* p) {
    u32x4 r;
    asm volatile("global_load_dwordx4 %0, %1, off sc0 sc1" : "=v"(r) : "v"(p) : "memory");
    return r;
}
__device__ __forceinline__ unsigned cload4(const void* p) {
    unsigned r;
    asm volatile("global_load_dword %0, %1, off sc0 sc1\n\ts_waitcnt vmcnt(0)"
                 : "=v"(r) : "v"(p) : "memory");
    return r;
}
__device__ __forceinline__ void cstore4(void* p, unsigned v) {
    asm volatile("global_store_dword %0, %1, off sc0 sc1" :: "v"(p), "v"(v) : "memory");
}

// ---------------- prep kernels ----------------
__global__ void conv_k(const float* __restrict__ in, u16* __restrict__ out, int n) {
    int i = blockIdx.x * 256 + threadIdx.x;
    if (i < n) out[i] = f2b(in[i]);
}
__global__ void embpad_k(const float* __restrict__ W_emb, u16* __restrict__ out) {
    int i = blockIdx.x * 256 + threadIdx.x;
    if (i < NVP * 128) out[i] = (i < NV * 128) ? f2b(W_emb[i]) : (u16)0;
}
__global__ void attnT_k(const float* __restrict__ We, const float* __restrict__ Wd, u16* __restrict__ out) {
    int i = blockIdx.x * 256 + threadIdx.x;
    if (i < 1024 * 512) {
        int n = i >> 9, k = i & 511;
        float v = (n < 512) ? We[k * 512 + n] : Wd[k * 512 + (n - 512)];
        out[i] = f2b(v);
    }
}
__global__ void projT_k(const float* __restrict__ Wp, u16* __restrict__ out) {
    int i = blockIdx.x * 256 + threadIdx.x;
    if (i < 1536 * 128) {
        int k = i >> 7, e = i & 127;
        out[i] = f2b(Wp[e * 1536 + k]);
    }
}
__global__ void gather_k(const float* __restrict__ W_emb, const int* __restrict__ tgt, u16* __restrict__ out) {
    int i = blockIdx.x * 256 + threadIdx.x;
    if (i < NR * 128) {
        int r = i >> 7, e = i & 127;
        out[i] = f2b(W_emb[(size_t)tgt[r] * 128 + e]);
    }
}
__global__ void init_k(const float* __restrict__ c0, const float* __restrict__ h0,
                       u16* __restrict__ hb0) {
    int i = blockIdx.x * 256 + threadIdx.x;
    if (i < 8192) { hb0[i] = f2b(h0[i]); }
    (void)c0;
}

// h_e [s][b][512] f32 -> h_eB [b][448][512] bf16 (pad s zero), h_eT [b][512][448] bf16
__global__ __launch_bounds__(256) void prep_he_k(const float* __restrict__ h_e,
                                                 u16* __restrict__ h_eB, u16* __restrict__ h_eT) {
    __shared__ u16 tile[64][68];
    const int st = blockIdx.x, b = blockIdx.y, tid = threadIdx.x;
    for (int dc = 0; dc < 8; dc++) {
        const int d0 = dc * 64;
#pragma unroll
        for (int k = 0; k < 4; k++) {
            int o = k * 256 + tid;
            int si = o >> 4, d4 = (o & 15) * 4;
            int s = st * 64 + si;
            float4 f = make_float4(0.f, 0.f, 0.f, 0.f);
            if (s < 400) f = *(const float4*)&h_e[((size_t)s * 16 + b) * 512 + d0 + d4];
            tile[si][d4 + 0] = f2b(f.x); tile[si][d4 + 1] = f2b(f.y);
            tile[si][d4 + 2] = f2b(f.z); tile[si][d4 + 3] = f2b(f.w);
        }
        __syncthreads();
#pragma unroll
        for (int k = 0; k < 4; k++) {
            int o = k * 256 + tid;
            int si = o >> 4, d4 = (o & 15) * 4;
            ushort4 u; u.x = tile[si][d4]; u.y = tile[si][d4 + 1]; u.z = tile[si][d4 + 2]; u.w = tile[si][d4 + 3];
            *(ushort4*)&h_eB[((size_t)b * 448 + st * 64 + si) * 512 + d0 + d4] = u;
        }
#pragma unroll
        for (int k = 0; k < 4; k++) {
            int o = k * 256 + tid;
            int di = o >> 4, s4 = (o & 15) * 4;
            ushort4 u; u.x = tile[s4][di]; u.y = tile[s4 + 1][di]; u.z = tile[s4 + 2][di]; u.w = tile[s4 + 3][di];
            *(ushort4*)&h_eT[((size_t)b * 512 + d0 + di) * 448 + st * 64 + s4] = u;
        }
        __syncthreads();
    }
}

// hd [(u*16+b)][512] f32 -> hdUB [b][64][512] bf16 (pad u zero), hdT [b][512][64] bf16
__global__ __launch_bounds__(256) void prep_hd_k(const float* __restrict__ hd,
                                                 u16* __restrict__ hdUB, u16* __restrict__ hdT) {
    __shared__ u16 tile[64][68];
    const int b = blockIdx.x, tid = threadIdx.x;
    for (int dc = 0; dc < 8; dc++) {
        const int d0 = dc * 64;
#pragma unroll
        for (int k = 0; k < 4; k++) {
            int o = k * 256 + tid;
            int ui = o >> 4, d4 = (o & 15) * 4;
            float4 f = make_float4(0.f, 0.f, 0.f, 0.f);
            if (ui < 60) f = *(const float4*)&hd[((size_t)ui * 16 + b) * 512 + d0 + d4];
            tile[ui][d4 + 0] = f2b(f.x); tile[ui][d4 + 1] = f2b(f.y);
            tile[ui][d4 + 2] = f2b(f.z); tile[ui][d4 + 3] = f2b(f.w);
        }
        __syncthreads();
#pragma unroll
        for (int k = 0; k < 4; k++) {
            int o = k * 256 + tid;
            int ui = o >> 4, d4 = (o & 15) * 4;
            ushort4 u; u.x = tile[ui][d4]; u.y = tile[ui][d4 + 1]; u.z = tile[ui][d4 + 2]; u.w = tile[ui][d4 + 3];
            *(ushort4*)&hdUB[((size_t)b * 64 + ui) * 512 + d0 + d4] = u;
        }
#pragma unroll
        for (int k = 0; k < 4; k++) {
            int o = k * 256 + tid;
            int di = o >> 4, u4 = (o & 15) * 4;
            ushort4 u; u.x = tile[u4][di]; u.y = tile[u4 + 1][di]; u.z = tile[u4 + 2][di]; u.w = tile[u4 + 3][di];
            *(ushort4*)&hdT[((size_t)b * 512 + d0 + di) * 64 + u4] = u;
        }
        __syncthreads();
    }
}

// q [(t*16+b)][1024] f32 -> qeB [b][64][512], qdB [b][64][512] bf16 (pad t zero)
__global__ void qprep_k(const float* __restrict__ q, u16* __restrict__ qeB, u16* __restrict__ qdB) {
    const int t = blockIdx.x, b = blockIdx.y, tid = threadIdx.x;
    const int o = tid * 4;
    float4 f = make_float4(0.f, 0.f, 0.f, 0.f);
    if (t < 60) f = *(const float4*)&q[((size_t)t * 16 + b) * 1024 + o];
    ushort4 u; u.x = f2b(f.x); u.y = f2b(f.y); u.z = f2b(f.z); u.w = f2b(f.w);
    if (o < 512) *(ushort4*)&qeB[((size_t)b * 64 + t) * 512 + o] = u;
    else         *(ushort4*)&qdB[((size_t)b * 64 + t) * 512 + (o - 512)] = u;
}

// ---------------- 64x64 bf16 MFMA GEMM, f32 out (small mats) ----------------
__global__ __launch_bounds__(256) void gemm64_k(
    const u16* __restrict__ A, const u16* __restrict__ Bm,
    int K, int ldC, float* __restrict__ outF,
    const float* __restrict__ bias1, const float* __restrict__ bias2)
{
    __shared__ u16 Al[64 * 40];
    __shared__ u16 Bl[64 * 40];
    const int tid = threadIdx.x;
    const int wv = tid >> 6, ln = tid & 63;
    const int bn = blockIdx.x, bm = blockIdx.y;
    const int srow = tid >> 2;
    const int skc = (tid & 3) * 8;
    const size_t aoff = (size_t)(bm * 64 + srow) * K + skc;
    const size_t boff = (size_t)(bn * 64 + srow) * K + skc;
    f32x4 acc[4];
#pragma unroll
    for (int t = 0; t < 4; t++) acc[t] = (f32x4){0.f, 0.f, 0.f, 0.f};
    const int fra = (wv * 16 + (ln & 15)) * 40 + (ln >> 4) * 8;
    for (int kb = 0; kb < K; kb += 32) {
        *(bf16x8*)&Al[srow * 40 + skc] = *(const bf16x8*)&A[aoff + kb];
        *(bf16x8*)&Bl[srow * 40 + skc] = *(const bf16x8*)&Bm[boff + kb];
        __syncthreads();
        bf16x8 af = *(const bf16x8*)&Al[fra];
#pragma unroll
        for (int t = 0; t < 4; t++) {
            bf16x8 bfr = *(const bf16x8*)&Bl[(t * 16 + (ln & 15)) * 40 + (ln >> 4) * 8];
            acc[t] = __builtin_amdgcn_mfma_f32_16x16x32_bf16(af, bfr, acc[t], 0, 0, 0);
        }
        __syncthreads();
    }
    const int rl = wv * 16 + (ln >> 4) * 4;
    const int cl = (ln & 15);
#pragma unroll
    for (int t = 0; t < 4; t++) {
        int col = bn * 64 + t * 16 + cl;
        float bv = 0.f;
        if (bias1) bv += bias1[col];
        if (bias2) bv += bias2[col];
#pragma unroll
        for (int r = 0; r < 4; r++)
            outF[(size_t)(bm * 64 + rl + r) * ldC + col] = acc[t][r] + bv;
    }
}

// ---------------- batched 64-wide A*B^T GEMM (M=64), f32 out ----------------
__global__ __launch_bounds__(256) void gemm_b_k(
    const u16* __restrict__ A, long sA,
    const u16* __restrict__ Bm, long sB, int K,
    float* __restrict__ C, long sC, int ldC)
{
    __shared__ u16 Al[64 * 40];
    __shared__ u16 Bl[64 * 40];
    const int tid = threadIdx.x;
    const int wv = tid >> 6, ln = tid & 63;
    const int bn = blockIdx.x, bz = blockIdx.z;
    A += (size_t)bz * sA; Bm += (size_t)bz * sB; C += (size_t)bz * sC;
    const int srow = tid >> 2;
    const int skc = (tid & 3) * 8;
    const size_t aoff = (size_t)srow * K + skc;
    const size_t boff = (size_t)(bn * 64 + srow) * K + skc;
    f32x4 acc[4];
#pragma unroll
    for (int t = 0; t < 4; t++) acc[t] = (f32x4){0.f, 0.f, 0.f, 0.f};
    const int fra = (wv * 16 + (ln & 15)) * 40 + (ln >> 4) * 8;
    for (int kb = 0; kb < K; kb += 32) {
        *(bf16x8*)&Al[srow * 40 + skc] = *(const bf16x8*)&A[aoff + kb];
        *(bf16x8*)&Bl[srow * 40 + skc] = *(const bf16x8*)&Bm[boff + kb];
        __syncthreads();
        bf16x8 af = *(const bf16x8*)&Al[fra];
#pragma unroll
        for (int t = 0; t < 4; t++) {
            bf16x8 bfr = *(const bf16x8*)&Bl[(t * 16 + (ln & 15)) * 40 + (ln >> 4) * 8];
            acc[t] = __builtin_amdgcn_mfma_f32_16x16x32_bf16(af, bfr, acc[t], 0, 0, 0);
        }
        __syncthreads();
    }
    const int rl = wv * 16 + (ln >> 4) * 4;
    const int cl = (ln & 15);
#pragma unroll
    for (int t = 0; t < 4; t++) {
        int col = bn * 64 + t * 16 + cl;
#pragma unroll
        for (int r = 0; r < 4; r++)
            C[(size_t)(rl + r) * ldC + col] = acc[t][r];
    }
}

// ---------------- 128x128 m97-style GEMM: MODE1 tanh->bf16, MODE2 streaming LSE + targ ----------------
template<int MODE>
__global__ __launch_bounds__(256) void gemm128_k(
    const u16* __restrict__ A, const u16* __restrict__ Bm, const int K,
    u16* __restrict__ outB, const int ldO,
    const float* __restrict__ bias,
    float* __restrict__ pmax, float* __restrict__ psum, const int vc0,
    const int* __restrict__ tgt, float* __restrict__ lt)
{
    __shared__ u16 Al[128 * 32];
    __shared__ u16 Bl[128 * 32];
    const int tid = threadIdx.x;
    const int w = tid >> 6, ln = tid & 63;
    const int wr = w >> 1, wc = w & 1;
    const int bn = blockIdx.x, bm = blockIdx.y;
    const int srow = w * 16 + (ln >> 2);
    const int scol = (ln & 3) * 8;
    const u16* ag = A + (size_t)bm * 128 * K + (size_t)srow * K + scol;
    const u16* bg = Bm + (size_t)bn * 128 * K + (size_t)srow * K + scol;
    u16* la = &Al[w * 16 * 32];
    u16* lb = &Bl[w * 16 * 32];
    f32x4 acc[4][4];
#pragma unroll
    for (int m = 0; m < 4; m++)
#pragma unroll
        for (int n = 0; n < 4; n++) acc[m][n] = (f32x4){0.f, 0.f, 0.f, 0.f};
    const int ra = (wr * 64 + (ln & 15)) * 32 + (ln >> 4) * 8;
    const int rb = (wc * 64 + (ln & 15)) * 32 + (ln >> 4) * 8;

    for (int kb = 0; kb < K; kb += 32) {
        gload16(ag + kb, la);
        gload16(ag + (size_t)64 * K + kb, la + 64 * 32);
        gload16(bg + kb, lb);
        gload16(bg + (size_t)64 * K + kb, lb + 64 * 32);
        __syncthreads();
        bf16x8 af[4], bfr[4];
#pragma unroll
        for (int m = 0; m < 4; m++) af[m] = *(const bf16x8*)&Al[ra + m * 16 * 32];
#pragma unroll
        for (int n = 0; n < 4; n++) bfr[n] = *(const bf16x8*)&Bl[rb + n * 16 * 32];
#pragma unroll
        for (int m = 0; m < 4; m++)
#pragma unroll
            for (int n = 0; n < 4; n++)
                acc[m][n] = __builtin_amdgcn_mfma_f32_16x16x32_bf16(af[m], bfr[n], acc[m][n], 0, 0, 0);
        __syncthreads();
    }

    const int cl = ln & 15, rg = ln >> 4;
    if (MODE == 1) {
#pragma unroll
        for (int m = 0; m < 4; m++) {
            int row0 = bm * 128 + wr * 64 + m * 16 + rg * 4;
#pragma unroll
            for (int n = 0; n < 4; n++) {
                int col = bn * 128 + wc * 64 + n * 16 + cl;
#pragma unroll
                for (int r = 0; r < 4; r++)
                    outB[(size_t)(row0 + r) * ldO + col] = f2b(tanhf(acc[m][n][r]));
            }
        }
    } else {
        const int cbg = (vc0 >> 6) + bn * 2 + wc;
        float bo[4]; int vg[4];
#pragma unroll
        for (int n = 0; n < 4; n++) {
            vg[n] = vc0 + bn * 128 + wc * 64 + n * 16 + cl;
            bo[n] = (vg[n] < NV) ? bias[vg[n]] : 0.f;
        }
#pragma unroll
        for (int m = 0; m < 4; m++) {
            int row0 = bm * 128 + wr * 64 + m * 16 + rg * 4;
#pragma unroll
            for (int r = 0; r < 4; r++) {
                int row = row0 + r;
                int tv = (row < NR) ? tgt[row] : -1;
                float lg[4]; float mm = -1e30f;
#pragma unroll
                for (int n = 0; n < 4; n++) {
                    lg[n] = (vg[n] < NV) ? (acc[m][n][r] + bo[n]) : -1e30f;
                    mm = fmaxf(mm, lg[n]);
                    if (vg[n] == tv) lt[row] = lg[n];
                }
                mm = fmaxf(mm, __shfl_xor(mm, 1, 64));
                mm = fmaxf(mm, __shfl_xor(mm, 2, 64));
                mm = fmaxf(mm, __shfl_xor(mm, 4, 64));
                mm = fmaxf(mm, __shfl_xor(mm, 8, 64));
                float s = 0.f;
#pragma unroll
                for (int n = 0; n < 4; n++) s += __expf(lg[n] - mm);
                s += __shfl_xor(s, 1, 64); s += __shfl_xor(s, 2, 64);
                s += __shfl_xor(s, 4, 64); s += __shfl_xor(s, 8, 64);
                if (cl == 0 && row < NR) {
                    pmax[(size_t)cbg * NR + row] = mm;
                    psum[(size_t)cbg * NR + row] = s;
                }
            }
        }
    }
}

// ---------------- persistent LSTM: all 60 steps, 32 blocks ----------------
// Cross-block exchange via Infinity-Cache-coherent (sc0 sc1) ops.
// Barrier: per-block flag stores + wave-0 polling. NO contended RMW, NO agent fences.
__global__ __launch_bounds__(256) void lstm_all(
    const u16* __restrict__ WhhB, u16* __restrict__ hB,
    const float* __restrict__ preGI, const float* __restrict__ c0,
    float* __restrict__ hd, u16* __restrict__ hdB, unsigned* __restrict__ bar)
{
    __shared__ float gl[1024];
    const int tid = threadIdx.x;
    const int g = tid >> 6, ln = tid & 63;
    const int dt = blockIdx.x;
    const int arow = (g * 512 + dt * 16 + (ln & 15)) * 512 + ((ln >> 4) * 8);
    // W_hh rows for this block stay in registers across all 60 steps
    bf16x8 aw[16];
#pragma unroll
    for (int kb = 0; kb < 16; kb++) aw[kb] = *(const bf16x8*)&WhhB[arow + kb * 32];
    const int b = tid >> 4, dl = tid & 15;
    const int d = dt * 16 + dl;
    float c = c0[b * 512 + d];
    const size_t brow_b = ((size_t)(ln & 15) * 512 + (size_t)(ln >> 4) * 8) * 2; // byte offset of B-fragment

    for (int t = 0; t < 60; t++) {
        const char* hin = (const char*)(hB + (size_t)(t & 1) * 8192);
        // prefetch full h (16B x 16) via coherent loads, single drain
        u32x4 hv[16];
#pragma unroll
        for (int kb = 0; kb < 16; kb++)
            hv[kb] = cload16_async(hin + brow_b + (size_t)kb * 64);
        asm volatile("s_waitcnt vmcnt(0)" ::: "memory");
        __builtin_amdgcn_sched_barrier(0);
        f32x4 acc = {0.f, 0.f, 0.f, 0.f};
#pragma unroll
        for (int kb = 0; kb < 16; kb++) {
            union { u32x4 u; bf16x8 h; } cv; cv.u = hv[kb];
            acc = __builtin_amdgcn_mfma_f32_16x16x32_bf16(aw[kb], cv.h, acc, 0, 0, 0);
        }
#pragma unroll
        for (int r = 0; r < 4; r++)
            gl[g * 256 + ((ln >> 4) * 4 + r) * 16 + (ln & 15)] = acc[r];
        __syncthreads();
        const float* pg = preGI + (size_t)t * 16 * 2048;
        float gi = gl[0 * 256 + dl * 16 + b] + pg[b * 2048 + 0 * 512 + d];
        float gf = gl[1 * 256 + dl * 16 + b] + pg[b * 2048 + 1 * 512 + d];
        float gg = gl[2 * 256 + dl * 16 + b] + pg[b * 2048 + 2 * 512 + d];
        float go = gl[3 * 256 + dl * 16 + b] + pg[b * 2048 + 3 * 512 + d];
        c = sigm(gf) * c + sigm(gi) * tanhf(gg);
        float h = sigm(go) * tanhf(c);
        hd[(size_t)t * 8192 + b * 512 + d] = h;           // normal stores (read after kernel end)
        u16 hb = f2b(h);
        hdB[(size_t)t * 8192 + b * 512 + d] = hb;
        // exchange store: pack 2 bf16 (d even: [d | d+1]) -> coherent dword store
        float ho = __shfl_xor(h, 1, 64);                  // partner lane: same b, dl^1
        u16 hb2 = f2b(ho);
        if ((dl & 1) == 0) {
            unsigned pk = (unsigned)hb | ((unsigned)hb2 << 16);
            char* hout = (char*)(hB + (size_t)((t & 1) ^ 1) * 8192);
            cstore4(hout + ((size_t)b * 512 + d) * 2, pk);
        }
        // drain own stores to IC, then signal own flag; wave 0 polls all 32 flags
        asm volatile("s_waitcnt vmcnt(0)" ::: "memory");
        __syncthreads();
        if (tid == 0) cstore4(&bar[dt], (unsigned)(t + 1));
        if (tid < 64) {
            const unsigned target = (unsigned)(t + 1);
            while (true) {
                unsigned v = target;
                if (ln < 32) v = cload4(&bar[ln]);
                if (__all(v >= target)) break;
                __builtin_amdgcn_s_sleep(1);
            }
        }
        __syncthreads();
    }
}

// ---------------- softmax kernels ----------------
__global__ __launch_bounds__(256) void softmax_e_k(
    const float* __restrict__ Se, const float* __restrict__ algn,
    u16* __restrict__ PeB, float* __restrict__ copysum)
{
    const int wid = blockIdx.x * 4 + (threadIdx.x >> 6);
    const int l = threadIdx.x & 63;
    const int t = wid >> 4, b = wid & 15;
    const float* srow = &Se[((size_t)b * 64 + t) * 448];
    float v[7];
    float m = -1e30f;
#pragma unroll
    for (int i = 0; i < 7; i++) {
        int s = l + i * 64;
        v[i] = (s < 400) ? srow[s] : -1e30f;
        m = fmaxf(m, v[i]);
    }
#pragma unroll
    for (int mk = 1; mk < 64; mk <<= 1) m = fmaxf(m, __shfl_xor(m, mk, 64));
    const float* arow = &algn[((size_t)t * 16 + b) * 400];
    float se = 0.f, ca = 0.f;
#pragma unroll
    for (int i = 0; i < 7; i++) {
        int s = l + i * 64;
        float e = (s < 400) ? __expf(v[i] - m) : 0.f;
        v[i] = e; se += e;
        if (s < 400) ca += e * arow[s];
    }
#pragma unroll
    for (int mk = 1; mk < 64; mk <<= 1) { se += __shfl_xor(se, mk, 64); ca += __shfl_xor(ca, mk, 64); }
    float inv = 1.f / se;
#pragma unroll
    for (int i = 0; i < 7; i++) {
        int s = l + i * 64;
        PeB[((size_t)b * 64 + t) * 448 + s] = f2b(v[i] * inv);
    }
    if (l == 0) copysum[t * 16 + b] = ca * inv;
}

__global__ __launch_bounds__(256) void softmax_d_k(const float* __restrict__ Sd, u16* __restrict__ PdB)
{
    const int wid = blockIdx.x * 4 + (threadIdx.x >> 6);
    const int l = threadIdx.x & 63;
    const int t = wid >> 4, b = wid & 15;
    float v = Sd[((size_t)b * 64 + t) * 64 + l];
    bool ok = (l <= t) && (l < 60);
    v = ok ? v : -1e30f;
    float m = v;
#pragma unroll
    for (int mk = 1; mk < 64; mk <<= 1) m = fmaxf(m, __shfl_xor(m, mk, 64));
    float e = ok ? __expf(v - m) : 0.f;
    float se = e;
#pragma unroll
    for (int mk = 1; mk < 64; mk <<= 1) se += __shfl_xor(se, mk, 64);
    float p = (t == 0) ? 0.f : e / se;
    PdB[((size_t)b * 64 + t) * 64 + l] = f2b(p);
}

// ---------------- cat assembly + p_switch ----------------
__global__ __launch_bounds__(256) void cat_k(
    const float* __restrict__ hd, const float* __restrict__ ce2, const float* __restrict__ cd2,
    const float* __restrict__ W_u, const float* __restrict__ b_u,
    u16* __restrict__ catB, float* __restrict__ p_switch)
{
    const int r = blockIdx.x, tid = threadIdx.x;
    if (r >= NR) {
        for (int j = tid; j < 1536; j += 256) catB[(size_t)r * 1536 + j] = 0;
        return;
    }
    const int t = r >> 4, b = r & 15;
    float partial = 0.f;
    for (int j = tid; j < 1536; j += 256) {
        float v;
        if (j < 512) v = hd[(size_t)r * 512 + j];
        else if (j < 1024) v = ce2[((size_t)b * 64 + t) * 512 + (j - 512)];
        else v = cd2[((size_t)b * 64 + t) * 512 + (j - 1024)];
        catB[(size_t)r * 1536 + j] = f2b(v);
        partial += v * W_u[j];
    }
#pragma unroll
    for (int mk = 1; mk < 64; mk <<= 1) partial += __shfl_xor(partial, mk, 64);
    __shared__ float red[4];
    if ((tid & 63) == 0) red[tid >> 6] = partial;
    __syncthreads();
    if (tid == 0) {
        float u = red[0] + red[1] + red[2] + red[3] + b_u[0];
        p_switch[r] = 1.f / (1.f + __expf(-u));
    }
}

// ---------------- per-row LSE combine (wave per row) ----------------
__global__ __launch_bounds__(256) void rowred_k(
    const float* __restrict__ pmax, const float* __restrict__ psum,
    const float* __restrict__ lt, const float* __restrict__ p_switch,
    const float* __restrict__ copysum, const int* __restrict__ tgt,
    float* __restrict__ terms)
{
    const int r = blockIdx.x * 4 + (threadIdx.x >> 6);
    const int l = threadIdx.x & 63;
    float m = -1e30f, s = 0.f;
    for (int cb = l; cb < NCB; cb += 64) {
        float me = pmax[(size_t)cb * NR + r];
        float se = psum[(size_t)cb * NR + r];
        float M2 = fmaxf(m, me);
        s = s * __expf(m - M2) + se * __expf(me - M2);
        m = M2;
    }
#pragma unroll
    for (int mk = 1; mk < 64; mk <<= 1) {
        float mo = __shfl_xor(m, mk, 64);
        float so = __shfl_xor(s, mk, 64);
        float M2 = fmaxf(m, mo);
        s = s * __expf(m - M2) + so * __expf(mo - M2);
        m = M2;
    }
    if (l == 0) {
        float ps = p_switch[r];
        float tg = (1.f - ps) * __expf(lt[r] - m) / s;
        float tc = ps * copysum[r];
        terms[r] = (tgt[r] != 0) ? -logf(tg + tc + 2e-12f) : 0.f;
    }
}

__global__ __launch_bounds__(256) void final_k(const float* __restrict__ terms, float* __restrict__ out)
{
    const int tid = threadIdx.x;
    float p = 0.f;
    for (int i = tid; i < NR; i += 256) p += terms[i];
#pragma unroll
    for (int mk = 1; mk < 64; mk <<= 1) p += __shfl_xor(p, mk, 64);
    __shared__ float red[4];
    if ((tid & 63) == 0) red[tid >> 6] = p;
    __syncthreads();
    if (tid == 0) out[0] = red[0] + red[1] + red[2] + red[3];
}

// ---------------- host launch ----------------
extern "C" void kernel_launch(void* const* d_in, const int* in_sizes, int n_in,
                              void* d_out, int out_size, void* d_ws, size_t ws_size,
                              hipStream_t stream)
{
    const int*   tgt    = (const int*)d_in[0];
    const float* algn   = (const float*)d_in[2];
    const float* h_e    = (const float*)d_in[3];
    const float* h0     = (const float*)d_in[4];
    const float* c0     = (const float*)d_in[5];
    const float* W_emb  = (const float*)d_in[6];
    const float* W_ih   = (const float*)d_in[7];
    const float* W_hh   = (const float*)d_in[8];
    const float* b_ih   = (const float*)d_in[9];
    const float* b_hh   = (const float*)d_in[10];
    const float* W_ae   = (const float*)d_in[11];
    const float* W_ad   = (const float*)d_in[12];
    const float* W_proj = (const float*)d_in[13];
    const float* W_u    = (const float*)d_in[14];
    const float* b_u    = (const float*)d_in[15];
    const float* b_out  = (const float*)d_in[16];
    (void)in_sizes; (void)n_in; (void)out_size; (void)ws_size;

    char* ws = (char*)d_ws;
    size_t off = 0;
    auto alloc = [&](size_t bytes) -> char* {
        char* p = ws + off;
        off += (bytes + 255) & ~(size_t)255;
        return p;
    };
    u16* wbuf    = (u16*)alloc((size_t)12800 * 1536 * 2);   // also overlaid: attention scratch
    u16* catB    = (u16*)alloc((size_t)1024 * 1536 * 2);
    u16* WprojT  = (u16*)alloc((size_t)1536 * 128 * 2);
    u16* WihB    = (u16*)alloc((size_t)2048 * 128 * 2);
    u16* WhhB    = (u16*)alloc((size_t)2048 * 512 * 2);
    u16* WattnT  = (u16*)alloc((size_t)1024 * 512 * 2);
    u16* WembB   = (u16*)alloc((size_t)NVP * 128 * 2);
    u16* embB    = (u16*)alloc((size_t)NR * 128 * 2);
    u16* hdB     = (u16*)alloc((size_t)NR * 512 * 2);
    u16* hB      = (u16*)alloc((size_t)2 * 8192 * 2);
    float* preGI = (float*)alloc((size_t)NR * 2048 * 4);
    float* hd    = (float*)alloc((size_t)NR * 512 * 4);
    float* q     = (float*)alloc((size_t)NR * 1024 * 4);
    float* p_sw  = (float*)alloc(NR * 4);
    float* copys = (float*)alloc(NR * 4);
    float* lt    = (float*)alloc(NR * 4);
    float* terms = (float*)alloc(NR * 4);
    float* pmax  = (float*)alloc((size_t)NCB * NR * 4);
    float* psum  = (float*)alloc((size_t)NCB * NR * 4);
    unsigned* bar = (unsigned*)alloc(256);

    // attention scratch overlaid into wbuf (wbuf used only after cat_k)
    u16* h_eB = wbuf;                      // 16*448*512
    u16* h_eT = h_eB + (size_t)16 * 448 * 512;
    u16* qeB  = h_eT + (size_t)16 * 448 * 512;  // 16*64*512
    u16* qdB  = qeB + (size_t)16 * 64 * 512;
    u16* hdUB = qdB + (size_t)16 * 64 * 512;
    u16* hdT  = hdUB + (size_t)16 * 64 * 512;
    u16* PeB  = hdT + (size_t)16 * 64 * 512;    // 16*64*448
    u16* PdB  = PeB + (size_t)16 * 64 * 448;    // 16*64*64
    float* Se = (float*)(PdB + (size_t)16 * 64 * 64);   // 16*64*448 f32
    float* Sd = Se + (size_t)16 * 64 * 448;             // 16*64*64
    float* ce2 = Sd + (size_t)16 * 64 * 64;             // 16*64*512
    float* cd2 = ce2 + (size_t)16 * 64 * 512;           // 16*64*512

    // prep
    conv_k<<<dim3((2048 * 128 + 255) / 256), 256, 0, stream>>>(W_ih, WihB, 2048 * 128);
    conv_k<<<dim3((2048 * 512 + 255) / 256), 256, 0, stream>>>(W_hh, WhhB, 2048 * 512);
    embpad_k<<<dim3((NVP * 128 + 255) / 256), 256, 0, stream>>>(W_emb, WembB);
    attnT_k<<<dim3((1024 * 512 + 255) / 256), 256, 0, stream>>>(W_ae, W_ad, WattnT);
    projT_k<<<dim3((1536 * 128 + 255) / 256), 256, 0, stream>>>(W_proj, WprojT);
    gather_k<<<dim3((NR * 128 + 255) / 256), 256, 0, stream>>>(W_emb, tgt, embB);
    init_k<<<dim3(32), 256, 0, stream>>>(c0, h0, hB);
    prep_he_k<<<dim3(7, 16), 256, 0, stream>>>(h_e, h_eB, h_eT);

    // preGI = emb @ W_ih^T + b_ih + b_hh
    gemm64_k<<<dim3(2048 / 64, NR / 64), 256, 0, stream>>>(embB, WihB, 128, 2048, preGI, b_ih, b_hh);

    // LSTM: all 60 steps in one persistent kernel, IC-coherent exchange
    hipMemsetAsync(bar, 0, 128, stream);
    lstm_all<<<dim3(32), 256, 0, stream>>>(WhhB, hB, preGI, c0, hd, hdB, bar);

    // q = hd @ [W_attn_e | W_attn_d]
    gemm64_k<<<dim3(1024 / 64, NR / 64), 256, 0, stream>>>(hdB, WattnT, 512, 1024, q, nullptr, nullptr);
    qprep_k<<<dim3(64, 16), 256, 0, stream>>>(q, qeB, qdB);
    prep_hd_k<<<dim3(16), 256, 0, stream>>>(hd, hdUB, hdT);

    // scores
    gemm_b_k<<<dim3(7, 1, 16), 256, 0, stream>>>(qeB, 64 * 512, h_eB, 448 * 512, 512, Se, 64 * 448, 448);
    gemm_b_k<<<dim3(1, 1, 16), 256, 0, stream>>>(qdB, 64 * 512, hdUB, 64 * 512, 512, Sd, 64 * 64, 64);
    softmax_e_k<<<dim3(240), 256, 0, stream>>>(Se, algn, PeB, copys);
    softmax_d_k<<<dim3(240), 256, 0, stream>>>(Sd, PdB);
    // PV
    gemm_b_k<<<dim3(8, 1, 16), 256, 0, stream>>>(PeB, 64 * 448, h_eT, 512 * 448, 448, ce2, 64 * 512, 512);
    gemm_b_k<<<dim3(8, 1, 16), 256, 0, stream>>>(PdB, 64 * 64, hdT, 512 * 64, 64, cd2, 64 * 512, 512);

    cat_k<<<dim3(1024), 256, 0, stream>>>(hd, ce2, cd2, W_u, b_u, catB, p_sw);

    // chunked: W_out chunk = tanh(W_emb @ W_proj), then cat @ chunk^T with streaming LSE + targ capture
    const int vc0s[4] = {0, 12800, 25600, 38400};
    const int nccs[4] = {12800, 12800, 12800, 11904};
    for (int c = 0; c < 4; c++) {
        gemm128_k<1><<<dim3(1536 / 128, nccs[c] / 128), 256, 0, stream>>>(
            WembB + (size_t)vc0s[c] * 128, WprojT, 128, wbuf, 1536,
            nullptr, nullptr, nullptr, 0, nullptr, nullptr);
        gemm128_k<2><<<dim3(nccs[c] / 128, 1024 / 128), 256, 0, stream>>>(
            catB, wbuf, 1536, nullptr, 0, b_out, pmax, psum, vc0s[c], tgt, lt);
    }

    rowred_k<<<dim3(240), 256, 0, stream>>>(pmax, psum, lt, p_sw, copys, tgt, terms);
    final_k<<<dim3(1), 256, 0, stream>>>(terms, (float*)d_out);
}

// Round 5
// 765.158 us; speedup vs baseline: 1.3629x; 1.1124x over previous
//
#include <hip/hip_runtime.h>

typedef unsigned short u16;
typedef __attribute__((ext_vector_type(8))) short bf16x8;
typedef __attribute__((ext_vector_type(4))) float f32x4;
typedef __attribute__((ext_vector_type(4))) unsigned u32x4;

#define NV 50257
#define NVP 50304
#define NR 960          // 60*16 rows
#define NCB 786         // 50304/64 col blocks

__device__ __forceinline__ u16 f2b(float x) {
    union { float f; unsigned u; } v; v.f = x;
    unsigned r = v.u + 0x7FFFu + ((v.u >> 16) & 1u);
    return (u16)(r >> 16);
}
__device__ __forceinline__ ushort4 f2b4(float4 f) {
    ushort4 u; u.x = f2b(f.x); u.y = f2b(f.y); u.z = f2b(f.z); u.w = f2b(f.w);
    return u;
}
__device__ __forceinline__ float b2f(u16 h) {
    union { unsigned u; float f; } v; v.u = ((unsigned)h) << 16;
    return v.f;
}
__device__ __forceinline__ float sigm(float x) { return 1.f / (1.f + __expf(-x)); }

__device__ __forceinline__ void gload16(const u16* g, u16* l) {
    __builtin_amdgcn_global_load_lds((const __attribute__((address_space(1))) void*)g,
                                     (__attribute__((address_space(3))) void*)l, 16, 0, 0);
}

// ---- cross-XCD coherent (L2-bypass, Infinity-Cache coherence point) ops ----
__device__ __forceinline__ u32x4 cload16_async(const void* p) {
    u32x4 r;
    asm volatile("global_load_dwordx4 %0, %1, off sc0 sc1" : "=v"(r) : "v"(p) : "memory");
    return r;
}
__device__ __forceinline__ unsigned cload4(const void* p) {
    unsigned r;
    asm volatile("global_load_dword %0, %1, off sc0 sc1\n\ts_waitcnt vmcnt(0)"
                 : "=v"(r) : "v"(p) : "memory");
    return r;
}
__device__ __forceinline__ void cstore4(void* p, unsigned v) {
    asm volatile("global_store_dword %0, %1, off sc0 sc1" :: "v"(p), "v"(v) : "memory");
}

// ---------------- fused prep: all weight conversions + transposes + gather + hX init ----------------
#define P_N0 65536                    // WihB  (x4)
#define P_N1 (P_N0 + 262144)          // WhhB  (x4)
#define P_N2 (P_N1 + 1609728)         // WembB pad (x4)
#define P_N3 (P_N2 + 524288)          // WattnT (scalar transpose)
#define P_N4 (P_N3 + 196608)          // WprojT (scalar transpose)
#define P_N5 (P_N4 + 30720)           // embB gather (x4)
#define P_N6 (P_N5 + 8192)            // hX init (scalar)
__global__ __launch_bounds__(256) void fused_prep_k(
    const float* __restrict__ W_ih, const float* __restrict__ W_hh,
    const float* __restrict__ W_emb, const float* __restrict__ We,
    const float* __restrict__ Wd, const float* __restrict__ Wp,
    const int* __restrict__ tgt, const float* __restrict__ h0,
    u16* __restrict__ WihB, u16* __restrict__ WhhB, u16* __restrict__ WembB,
    u16* __restrict__ WattnT, u16* __restrict__ WprojT, u16* __restrict__ embB,
    u16* __restrict__ hX)
{
    int i = blockIdx.x * 256 + threadIdx.x;
    if (i < P_N0) {
        ((ushort4*)WihB)[i] = f2b4(((const float4*)W_ih)[i]);
    } else if (i < P_N1) {
        i -= P_N0;
        ((ushort4*)WhhB)[i] = f2b4(((const float4*)W_hh)[i]);
    } else if (i < P_N2) {
        i -= P_N1;
        int e0 = i * 4;
        float4 f;
        if (e0 + 3 < NV * 128) f = ((const float4*)W_emb)[i];
        else {
            f.x = (e0 + 0 < NV * 128) ? W_emb[e0 + 0] : 0.f;
            f.y = (e0 + 1 < NV * 128) ? W_emb[e0 + 1] : 0.f;
            f.z = (e0 + 2 < NV * 128) ? W_emb[e0 + 2] : 0.f;
            f.w = (e0 + 3 < NV * 128) ? W_emb[e0 + 3] : 0.f;
        }
        ((ushort4*)WembB)[i] = f2b4(f);
    } else if (i < P_N3) {
        i -= P_N2;
        int n = i >> 9, k = i & 511;
        float v = (n < 512) ? We[k * 512 + n] : Wd[k * 512 + (n - 512)];
        WattnT[i] = f2b(v);
    } else if (i < P_N4) {
        i -= P_N3;
        int k = i >> 7, e = i & 127;
        WprojT[i] = f2b(Wp[e * 1536 + k]);
    } else if (i < P_N5) {
        i -= P_N4;
        int r = i >> 5, e = (i & 31) * 4;
        float4 f = *(const float4*)&W_emb[(size_t)tgt[r] * 128 + e];
        ((ushort4*)embB)[i] = f2b4(f);
    } else if (i < P_N6) {
        i -= P_N5;
        int b = i >> 9, d = i & 511;
        int blk = d >> 5, dl = d & 31;
        hX[blk * 512 + b * 32 + dl] = f2b(h0[i]);   // buffer 0
    }
}

// h_e [s][b][512] f32 -> h_eB [b][448][512] bf16 (pad s zero), h_eT [b][512][448] bf16
__global__ __launch_bounds__(256) void prep_he_k(const float* __restrict__ h_e,
                                                 u16* __restrict__ h_eB, u16* __restrict__ h_eT) {
    __shared__ u16 tile[64][68];
    const int st = blockIdx.x, b = blockIdx.y, tid = threadIdx.x;
    for (int dc = 0; dc < 8; dc++) {
        const int d0 = dc * 64;
#pragma unroll
        for (int k = 0; k < 4; k++) {
            int o = k * 256 + tid;
            int si = o >> 4, d4 = (o & 15) * 4;
            int s = st * 64 + si;
            float4 f = make_float4(0.f, 0.f, 0.f, 0.f);
            if (s < 400) f = *(const float4*)&h_e[((size_t)s * 16 + b) * 512 + d0 + d4];
            tile[si][d4 + 0] = f2b(f.x); tile[si][d4 + 1] = f2b(f.y);
            tile[si][d4 + 2] = f2b(f.z); tile[si][d4 + 3] = f2b(f.w);
        }
        __syncthreads();
#pragma unroll
        for (int k = 0; k < 4; k++) {
            int o = k * 256 + tid;
            int si = o >> 4, d4 = (o & 15) * 4;
            ushort4 u; u.x = tile[si][d4]; u.y = tile[si][d4 + 1]; u.z = tile[si][d4 + 2]; u.w = tile[si][d4 + 3];
            *(ushort4*)&h_eB[((size_t)b * 448 + st * 64 + si) * 512 + d0 + d4] = u;
        }
#pragma unroll
        for (int k = 0; k < 4; k++) {
            int o = k * 256 + tid;
            int di = o >> 4, s4 = (o & 15) * 4;
            ushort4 u; u.x = tile[s4][di]; u.y = tile[s4 + 1][di]; u.z = tile[s4 + 2][di]; u.w = tile[s4 + 3][di];
            *(ushort4*)&h_eT[((size_t)b * 512 + d0 + di) * 448 + st * 64 + s4] = u;
        }
        __syncthreads();
    }
}

// hd [(u*16+b)][512] f32 -> hdUB [b][64][512] bf16 (pad u zero), hdT [b][512][64] bf16
__global__ __launch_bounds__(256) void prep_hd_k(const float* __restrict__ hd,
                                                 u16* __restrict__ hdUB, u16* __restrict__ hdT) {
    __shared__ u16 tile[64][68];
    const int b = blockIdx.x, tid = threadIdx.x;
    for (int dc = 0; dc < 8; dc++) {
        const int d0 = dc * 64;
#pragma unroll
        for (int k = 0; k < 4; k++) {
            int o = k * 256 + tid;
            int ui = o >> 4, d4 = (o & 15) * 4;
            float4 f = make_float4(0.f, 0.f, 0.f, 0.f);
            if (ui < 60) f = *(const float4*)&hd[((size_t)ui * 16 + b) * 512 + d0 + d4];
            tile[ui][d4 + 0] = f2b(f.x); tile[ui][d4 + 1] = f2b(f.y);
            tile[ui][d4 + 2] = f2b(f.z); tile[ui][d4 + 3] = f2b(f.w);
        }
        __syncthreads();
#pragma unroll
        for (int k = 0; k < 4; k++) {
            int o = k * 256 + tid;
            int ui = o >> 4, d4 = (o & 15) * 4;
            ushort4 u; u.x = tile[ui][d4]; u.y = tile[ui][d4 + 1]; u.z = tile[ui][d4 + 2]; u.w = tile[ui][d4 + 3];
            *(ushort4*)&hdUB[((size_t)b * 64 + ui) * 512 + d0 + d4] = u;
        }
#pragma unroll
        for (int k = 0; k < 4; k++) {
            int o = k * 256 + tid;
            int di = o >> 4, u4 = (o & 15) * 4;
            ushort4 u; u.x = tile[u4][di]; u.y = tile[u4 + 1][di]; u.z = tile[u4 + 2][di]; u.w = tile[u4 + 3][di];
            *(ushort4*)&hdT[((size_t)b * 512 + d0 + di) * 64 + u4] = u;
        }
        __syncthreads();
    }
}

// q [(t*16+b)][1024] f32 -> qeB [b][64][512], qdB [b][64][512] bf16 (pad t zero)
__global__ void qprep_k(const float* __restrict__ q, u16* __restrict__ qeB, u16* __restrict__ qdB) {
    const int t = blockIdx.x, b = blockIdx.y, tid = threadIdx.x;
    const int o = tid * 4;
    float4 f = make_float4(0.f, 0.f, 0.f, 0.f);
    if (t < 60) f = *(const float4*)&q[((size_t)t * 16 + b) * 1024 + o];
    ushort4 u = f2b4(f);
    if (o < 512) *(ushort4*)&qeB[((size_t)b * 64 + t) * 512 + o] = u;
    else         *(ushort4*)&qdB[((size_t)b * 64 + t) * 512 + (o - 512)] = u;
}

// ---------------- 64x64 bf16 MFMA GEMM, f32 out (small mats) ----------------
__global__ __launch_bounds__(256) void gemm64_k(
    const u16* __restrict__ A, const u16* __restrict__ Bm,
    int K, int ldC, float* __restrict__ outF,
    const float* __restrict__ bias1, const float* __restrict__ bias2)
{
    __shared__ u16 Al[64 * 40];
    __shared__ u16 Bl[64 * 40];
    const int tid = threadIdx.x;
    const int wv = tid >> 6, ln = tid & 63;
    const int bn = blockIdx.x, bm = blockIdx.y;
    const int srow = tid >> 2;
    const int skc = (tid & 3) * 8;
    const size_t aoff = (size_t)(bm * 64 + srow) * K + skc;
    const size_t boff = (size_t)(bn * 64 + srow) * K + skc;
    f32x4 acc[4];
#pragma unroll
    for (int t = 0; t < 4; t++) acc[t] = (f32x4){0.f, 0.f, 0.f, 0.f};
    const int fra = (wv * 16 + (ln & 15)) * 40 + (ln >> 4) * 8;
    for (int kb = 0; kb < K; kb += 32) {
        *(bf16x8*)&Al[srow * 40 + skc] = *(const bf16x8*)&A[aoff + kb];
        *(bf16x8*)&Bl[srow * 40 + skc] = *(const bf16x8*)&Bm[boff + kb];
        __syncthreads();
        bf16x8 af = *(const bf16x8*)&Al[fra];
#pragma unroll
        for (int t = 0; t < 4; t++) {
            bf16x8 bfr = *(const bf16x8*)&Bl[(t * 16 + (ln & 15)) * 40 + (ln >> 4) * 8];
            acc[t] = __builtin_amdgcn_mfma_f32_16x16x32_bf16(af, bfr, acc[t], 0, 0, 0);
        }
        __syncthreads();
    }
    const int rl = wv * 16 + (ln >> 4) * 4;
    const int cl = (ln & 15);
#pragma unroll
    for (int t = 0; t < 4; t++) {
        int col = bn * 64 + t * 16 + cl;
        float bv = 0.f;
        if (bias1) bv += bias1[col];
        if (bias2) bv += bias2[col];
#pragma unroll
        for (int r = 0; r < 4; r++)
            outF[(size_t)(bm * 64 + rl + r) * ldC + col] = acc[t][r] + bv;
    }
}

// ---------------- batched 64-wide A*B^T GEMM (M=64), f32 out ----------------
__global__ __launch_bounds__(256) void gemm_b_k(
    const u16* __restrict__ A, long sA,
    const u16* __restrict__ Bm, long sB, int K,
    float* __restrict__ C, long sC, int ldC)
{
    __shared__ u16 Al[64 * 40];
    __shared__ u16 Bl[64 * 40];
    const int tid = threadIdx.x;
    const int wv = tid >> 6, ln = tid & 63;
    const int bn = blockIdx.x, bz = blockIdx.z;
    A += (size_t)bz * sA; Bm += (size_t)bz * sB; C += (size_t)bz * sC;
    const int srow = tid >> 2;
    const int skc = (tid & 3) * 8;
    const size_t aoff = (size_t)srow * K + skc;
    const size_t boff = (size_t)(bn * 64 + srow) * K + skc;
    f32x4 acc[4];
#pragma unroll
    for (int t = 0; t < 4; t++) acc[t] = (f32x4){0.f, 0.f, 0.f, 0.f};
    const int fra = (wv * 16 + (ln & 15)) * 40 + (ln >> 4) * 8;
    for (int kb = 0; kb < K; kb += 32) {
        *(bf16x8*)&Al[srow * 40 + skc] = *(const bf16x8*)&A[aoff + kb];
        *(bf16x8*)&Bl[srow * 40 + skc] = *(const bf16x8*)&Bm[boff + kb];
        __syncthreads();
        bf16x8 af = *(const bf16x8*)&Al[fra];
#pragma unroll
        for (int t = 0; t < 4; t++) {
            bf16x8 bfr = *(const bf16x8*)&Bl[(t * 16 + (ln & 15)) * 40 + (ln >> 4) * 8];
            acc[t] = __builtin_amdgcn_mfma_f32_16x16x32_bf16(af, bfr, acc[t], 0, 0, 0);
        }
        __syncthreads();
    }
    const int rl = wv * 16 + (ln >> 4) * 4;
    const int cl = (ln & 15);
#pragma unroll
    for (int t = 0; t < 4; t++) {
        int col = bn * 64 + t * 16 + cl;
#pragma unroll
        for (int r = 0; r < 4; r++)
            C[(size_t)(rl + r) * ldC + col] = acc[t][r];
    }
}

// ---------------- 128x128 m97-style GEMM: MODE1 tanh->bf16, MODE2 streaming LSE + targ ----------------
template<int MODE>
__global__ __launch_bounds__(256) void gemm128_k(
    const u16* __restrict__ A, const u16* __restrict__ Bm, const int K,
    u16* __restrict__ outB, const int ldO,
    const float* __restrict__ bias,
    float* __restrict__ pmax, float* __restrict__ psum, const int vc0,
    const int* __restrict__ tgt, float* __restrict__ lt)
{
    __shared__ u16 Al[128 * 32];
    __shared__ u16 Bl[128 * 32];
    const int tid = threadIdx.x;
    const int w = tid >> 6, ln = tid & 63;
    const int wr = w >> 1, wc = w & 1;
    const int bn = blockIdx.x, bm = blockIdx.y;
    const int srow = w * 16 + (ln >> 2);
    const int scol = (ln & 3) * 8;
    const u16* ag = A + (size_t)bm * 128 * K + (size_t)srow * K + scol;
    const u16* bg = Bm + (size_t)bn * 128 * K + (size_t)srow * K + scol;
    u16* la = &Al[w * 16 * 32];
    u16* lb = &Bl[w * 16 * 32];
    f32x4 acc[4][4];
#pragma unroll
    for (int m = 0; m < 4; m++)
#pragma unroll
        for (int n = 0; n < 4; n++) acc[m][n] = (f32x4){0.f, 0.f, 0.f, 0.f};
    const int ra = (wr * 64 + (ln & 15)) * 32 + (ln >> 4) * 8;
    const int rb = (wc * 64 + (ln & 15)) * 32 + (ln >> 4) * 8;

    for (int kb = 0; kb < K; kb += 32) {
        gload16(ag + kb, la);
        gload16(ag + (size_t)64 * K + kb, la + 64 * 32);
        gload16(bg + kb, lb);
        gload16(bg + (size_t)64 * K + kb, lb + 64 * 32);
        __syncthreads();
        bf16x8 af[4], bfr[4];
#pragma unroll
        for (int m = 0; m < 4; m++) af[m] = *(const bf16x8*)&Al[ra + m * 16 * 32];
#pragma unroll
        for (int n = 0; n < 4; n++) bfr[n] = *(const bf16x8*)&Bl[rb + n * 16 * 32];
#pragma unroll
        for (int m = 0; m < 4; m++)
#pragma unroll
            for (int n = 0; n < 4; n++)
                acc[m][n] = __builtin_amdgcn_mfma_f32_16x16x32_bf16(af[m], bfr[n], acc[m][n], 0, 0, 0);
        __syncthreads();
    }

    const int cl = ln & 15, rg = ln >> 4;
    if (MODE == 1) {
#pragma unroll
        for (int m = 0; m < 4; m++) {
            int row0 = bm * 128 + wr * 64 + m * 16 + rg * 4;
#pragma unroll
            for (int n = 0; n < 4; n++) {
                int col = bn * 128 + wc * 64 + n * 16 + cl;
#pragma unroll
                for (int r = 0; r < 4; r++)
                    outB[(size_t)(row0 + r) * ldO + col] = f2b(tanhf(acc[m][n][r]));
            }
        }
    } else {
        const int cbg = (vc0 >> 6) + bn * 2 + wc;
        float bo[4]; int vg[4];
#pragma unroll
        for (int n = 0; n < 4; n++) {
            vg[n] = vc0 + bn * 128 + wc * 64 + n * 16 + cl;
            bo[n] = (vg[n] < NV) ? bias[vg[n]] : 0.f;
        }
#pragma unroll
        for (int m = 0; m < 4; m++) {
            int row0 = bm * 128 + wr * 64 + m * 16 + rg * 4;
#pragma unroll
            for (int r = 0; r < 4; r++) {
                int row = row0 + r;
                int tv = (row < NR) ? tgt[row] : -1;
                float lg[4]; float mm = -1e30f;
#pragma unroll
                for (int n = 0; n < 4; n++) {
                    lg[n] = (vg[n] < NV) ? (acc[m][n][r] + bo[n]) : -1e30f;
                    mm = fmaxf(mm, lg[n]);
                    if (vg[n] == tv) lt[row] = lg[n];
                }
                mm = fmaxf(mm, __shfl_xor(mm, 1, 64));
                mm = fmaxf(mm, __shfl_xor(mm, 2, 64));
                mm = fmaxf(mm, __shfl_xor(mm, 4, 64));
                mm = fmaxf(mm, __shfl_xor(mm, 8, 64));
                float s = 0.f;
#pragma unroll
                for (int n = 0; n < 4; n++) s += __expf(lg[n] - mm);
                s += __shfl_xor(s, 1, 64); s += __shfl_xor(s, 2, 64);
                s += __shfl_xor(s, 4, 64); s += __shfl_xor(s, 8, 64);
                if (cl == 0 && row < NR) {
                    pmax[(size_t)cbg * NR + row] = mm;
                    psum[(size_t)cbg * NR + row] = s;
                }
            }
        }
    }
}

// ---------------- persistent LSTM: 60 steps, 16 blocks, trimmed critical path ----------------
// hX layout: [2 buf][16 blk][16 b][32 d] bf16 (1 KB per blk-slice).
// Per step: exchange stores -> vmcnt -> barrier -> tag -> (bulk hd stores) -> poll 16 tags.
__global__ __launch_bounds__(256) void lstm_all(
    const u16* __restrict__ WhhB, u16* __restrict__ hX,
    const float* __restrict__ preGI, const float* __restrict__ c0,
    float* __restrict__ hd, u16* __restrict__ hdB, unsigned* __restrict__ bar)
{
    __shared__ float gl[4 * 32 * 17];
    const int tid = threadIdx.x;
    const int g = tid >> 6, ln = tid & 63;
    const int dt = blockIdx.x;            // d-range [dt*32, dt*32+32)
    // W_hh rows in registers: gate g, 2 row-tiles of 16
    bf16x8 aw[2][16];
#pragma unroll
    for (int m = 0; m < 2; m++) {
        const int arow = (g * 512 + dt * 32 + m * 16 + (ln & 15)) * 512 + ((ln >> 4) * 8);
#pragma unroll
        for (int kb = 0; kb < 16; kb++) aw[m][kb] = *(const bf16x8*)&WhhB[arow + kb * 32];
    }
    const int b = tid >> 4, dp = tid & 15;
    const int d0 = dt * 32 + dp * 2;
    float c_0 = c0[b * 512 + d0];
    float c_1 = c0[b * 512 + d0 + 1];
    const int hoff = (ln & 15) * 64 + (ln >> 4) * 16;   // byte offset into a blk slice

    for (int t = 0; t < 60; t++) {
        const char* hin = (const char*)hX + (size_t)(t & 1) * 16384;
        u32x4 hv[16];
#pragma unroll
        for (int kb = 0; kb < 16; kb++)
            hv[kb] = cload16_async(hin + kb * 1024 + hoff);
        // force-issue preGI loads so they overlap the h-wait
        const float* pg = preGI + ((size_t)t * 16 + b) * 2048 + d0;
        float2 p0 = *(const float2*)&pg[0];
        float2 p1 = *(const float2*)&pg[512];
        float2 p2 = *(const float2*)&pg[1024];
        float2 p3 = *(const float2*)&pg[1536];
        asm volatile("" :: "v"(p0.x), "v"(p0.y), "v"(p1.x), "v"(p1.y),
                           "v"(p2.x), "v"(p2.y), "v"(p3.x), "v"(p3.y));
        asm volatile("s_waitcnt vmcnt(0)" ::: "memory");
        __builtin_amdgcn_sched_barrier(0);
        f32x4 acc0 = {0.f, 0.f, 0.f, 0.f}, acc1 = {0.f, 0.f, 0.f, 0.f};
#pragma unroll
        for (int kb = 0; kb < 16; kb++) {
            union { u32x4 u; bf16x8 h; } cv; cv.u = hv[kb];
            acc0 = __builtin_amdgcn_mfma_f32_16x16x32_bf16(aw[0][kb], cv.h, acc0, 0, 0, 0);
            acc1 = __builtin_amdgcn_mfma_f32_16x16x32_bf16(aw[1][kb], cv.h, acc1, 0, 0, 0);
        }
#pragma unroll
        for (int r = 0; r < 4; r++) {
            gl[(g * 32 + (ln >> 4) * 4 + r) * 17 + (ln & 15)] = acc0[r];
            gl[(g * 32 + 16 + (ln >> 4) * 4 + r) * 17 + (ln & 15)] = acc1[r];
        }
        __syncthreads();
        // combine: thread (b, dp) handles d-locals 2dp, 2dp+1
        const int dl0 = dp * 2;
        float i0 = gl[(0 * 32 + dl0) * 17 + b] + p0.x;
        float i1 = gl[(0 * 32 + dl0 + 1) * 17 + b] + p0.y;
        float f0 = gl[(1 * 32 + dl0) * 17 + b] + p1.x;
        float f1 = gl[(1 * 32 + dl0 + 1) * 17 + b] + p1.y;
        float g0 = gl[(2 * 32 + dl0) * 17 + b] + p2.x;
        float g1 = gl[(2 * 32 + dl0 + 1) * 17 + b] + p2.y;
        float o0 = gl[(3 * 32 + dl0) * 17 + b] + p3.x;
        float o1 = gl[(3 * 32 + dl0 + 1) * 17 + b] + p3.y;
        c_0 = sigm(f0) * c_0 + sigm(i0) * tanhf(g0);
        c_1 = sigm(f1) * c_1 + sigm(i1) * tanhf(g1);
        float h_0 = sigm(o0) * tanhf(c_0);
        float h_1 = sigm(o1) * tanhf(c_1);
        u16 hb0 = f2b(h_0), hb1 = f2b(h_1);
        unsigned pk = (unsigned)hb0 | ((unsigned)hb1 << 16);
        if (t < 59) {
            // exchange store first (critical path), drain, tag
            char* hout = (char*)hX + (size_t)((t & 1) ^ 1) * 16384;
            cstore4(hout + dt * 1024 + b * 64 + dp * 4, pk);
            asm volatile("s_waitcnt vmcnt(0)" ::: "memory");
            __syncthreads();
            if (tid == 0) cstore4(&bar[dt * 16], (unsigned)(t + 1));
        }
        // bulk outputs off the critical path
        *(float2*)&hd[(size_t)t * 8192 + b * 512 + d0] = make_float2(h_0, h_1);
        *(unsigned*)&hdB[(size_t)t * 8192 + b * 512 + d0] = pk;
        if (t < 59) {
            const unsigned target = (unsigned)(t + 1);
            while (true) {
                unsigned v = target;
                if (ln < 16) v = cload4(&bar[ln * 16]);
                if (__all(v >= target)) break;
                __builtin_amdgcn_s_sleep(1);
            }
        }
    }
}

// ---------------- fused softmax (enc blocks [0,240), dec blocks [240,480)) ----------------
__global__ __launch_bounds__(256) void softmax_ed_k(
    const float* __restrict__ Se, const float* __restrict__ algn,
    u16* __restrict__ PeB, float* __restrict__ copysum,
    const float* __restrict__ Sd, u16* __restrict__ PdB)
{
    const int l = threadIdx.x & 63;
    if (blockIdx.x < 240) {
        const int wid = blockIdx.x * 4 + (threadIdx.x >> 6);
        const int t = wid >> 4, b = wid & 15;
        const float* srow = &Se[((size_t)b * 64 + t) * 448];
        float v[7];
        float m = -1e30f;
#pragma unroll
        for (int i = 0; i < 7; i++) {
            int s = l + i * 64;
            v[i] = (s < 400) ? srow[s] : -1e30f;
            m = fmaxf(m, v[i]);
        }
#pragma unroll
        for (int mk = 1; mk < 64; mk <<= 1) m = fmaxf(m, __shfl_xor(m, mk, 64));
        const float* arow = &algn[((size_t)t * 16 + b) * 400];
        float se = 0.f, ca = 0.f;
#pragma unroll
        for (int i = 0; i < 7; i++) {
            int s = l + i * 64;
            float e = (s < 400) ? __expf(v[i] - m) : 0.f;
            v[i] = e; se += e;
            if (s < 400) ca += e * arow[s];
        }
#pragma unroll
        for (int mk = 1; mk < 64; mk <<= 1) { se += __shfl_xor(se, mk, 64); ca += __shfl_xor(ca, mk, 64); }
        float inv = 1.f / se;
#pragma unroll
        for (int i = 0; i < 7; i++) {
            int s = l + i * 64;
            PeB[((size_t)b * 64 + t) * 448 + s] = f2b(v[i] * inv);
        }
        if (l == 0) copysum[t * 16 + b] = ca * inv;
    } else {
        const int wid = (blockIdx.x - 240) * 4 + (threadIdx.x >> 6);
        const int t = wid >> 4, b = wid & 15;
        float v = Sd[((size_t)b * 64 + t) * 64 + l];
        bool ok = (l <= t) && (l < 60);
        v = ok ? v : -1e30f;
        float m = v;
#pragma unroll
        for (int mk = 1; mk < 64; mk <<= 1) m = fmaxf(m, __shfl_xor(m, mk, 64));
        float e = ok ? __expf(v - m) : 0.f;
        float se = e;
#pragma unroll
        for (int mk = 1; mk < 64; mk <<= 1) se += __shfl_xor(se, mk, 64);
        float p = (t == 0) ? 0.f : e / se;
        PdB[((size_t)b * 64 + t) * 64 + l] = f2b(p);
    }
}

// ---------------- cat assembly + p_switch ----------------
__global__ __launch_bounds__(256) void cat_k(
    const float* __restrict__ hd, const float* __restrict__ ce2, const float* __restrict__ cd2,
    const float* __restrict__ W_u, const float* __restrict__ b_u,
    u16* __restrict__ catB, float* __restrict__ p_switch)
{
    const int r = blockIdx.x, tid = threadIdx.x;
    if (r >= NR) {
        for (int j = tid; j < 1536; j += 256) catB[(size_t)r * 1536 + j] = 0;
        return;
    }
    const int t = r >> 4, b = r & 15;
    float partial = 0.f;
    for (int j = tid; j < 1536; j += 256) {
        float v;
        if (j < 512) v = hd[(size_t)r * 512 + j];
        else if (j < 1024) v = ce2[((size_t)b * 64 + t) * 512 + (j - 512)];
        else v = cd2[((size_t)b * 64 + t) * 512 + (j - 1024)];
        catB[(size_t)r * 1536 + j] = f2b(v);
        partial += v * W_u[j];
    }
#pragma unroll
    for (int mk = 1; mk < 64; mk <<= 1) partial += __shfl_xor(partial, mk, 64);
    __shared__ float red[4];
    if ((tid & 63) == 0) red[tid >> 6] = partial;
    __syncthreads();
    if (tid == 0) {
        float u = red[0] + red[1] + red[2] + red[3] + b_u[0];
        p_switch[r] = 1.f / (1.f + __expf(-u));
    }
}

// ---------------- per-row LSE combine (wave per row) ----------------
__global__ __launch_bounds__(256) void rowred_k(
    const float* __restrict__ pmax, const float* __restrict__ psum,
    const float* __restrict__ lt, const float* __restrict__ p_switch,
    const float* __restrict__ copysum, const int* __restrict__ tgt,
    float* __restrict__ terms)
{
    const int r = blockIdx.x * 4 + (threadIdx.x >> 6);
    const int l = threadIdx.x & 63;
    float m = -1e30f, s = 0.f;
    for (int cb = l; cb < NCB; cb += 64) {
        float me = pmax[(size_t)cb * NR + r];
        float se = psum[(size_t)cb * NR + r];
        float M2 = fmaxf(m, me);
        s = s * __expf(m - M2) + se * __expf(me - M2);
        m = M2;
    }
#pragma unroll
    for (int mk = 1; mk < 64; mk <<= 1) {
        float mo = __shfl_xor(m, mk, 64);
        float so = __shfl_xor(s, mk, 64);
        float M2 = fmaxf(m, mo);
        s = s * __expf(m - M2) + so * __expf(mo - M2);
        m = M2;
    }
    if (l == 0) {
        float ps = p_switch[r];
        float tg = (1.f - ps) * __expf(lt[r] - m) / s;
        float tc = ps * copysum[r];
        terms[r] = (tgt[r] != 0) ? -logf(tg + tc + 2e-12f) : 0.f;
    }
}

__global__ __launch_bounds__(256) void final_k(const float* __restrict__ terms, float* __restrict__ out)
{
    const int tid = threadIdx.x;
    float p = 0.f;
    for (int i = tid; i < NR; i += 256) p += terms[i];
#pragma unroll
    for (int mk = 1; mk < 64; mk <<= 1) p += __shfl_xor(p, mk, 64);
    __shared__ float red[4];
    if ((tid & 63) == 0) red[tid >> 6] = p;
    __syncthreads();
    if (tid == 0) out[0] = red[0] + red[1] + red[2] + red[3];
}

// ---------------- host launch ----------------
extern "C" void kernel_launch(void* const* d_in, const int* in_sizes, int n_in,
                              void* d_out, int out_size, void* d_ws, size_t ws_size,
                              hipStream_t stream)
{
    const int*   tgt    = (const int*)d_in[0];
    const float* algn   = (const float*)d_in[2];
    const float* h_e    = (const float*)d_in[3];
    const float* h0     = (const float*)d_in[4];
    const float* c0     = (const float*)d_in[5];
    const float* W_emb  = (const float*)d_in[6];
    const float* W_ih   = (const float*)d_in[7];
    const float* W_hh   = (const float*)d_in[8];
    const float* b_ih   = (const float*)d_in[9];
    const float* b_hh   = (const float*)d_in[10];
    const float* W_ae   = (const float*)d_in[11];
    const float* W_ad   = (const float*)d_in[12];
    const float* W_proj = (const float*)d_in[13];
    const float* W_u    = (const float*)d_in[14];
    const float* b_u    = (const float*)d_in[15];
    const float* b_out  = (const float*)d_in[16];
    (void)in_sizes; (void)n_in; (void)out_size; (void)ws_size;

    char* ws = (char*)d_ws;
    size_t off = 0;
    auto alloc = [&](size_t bytes) -> char* {
        char* p = ws + off;
        off += (bytes + 255) & ~(size_t)255;
        return p;
    };
    u16* wbuf    = (u16*)alloc((size_t)12800 * 1536 * 2);   // also overlaid: attention scratch
    u16* catB    = (u16*)alloc((size_t)1024 * 1536 * 2);
    u16* WprojT  = (u16*)alloc((size_t)1536 * 128 * 2);
    u16* WihB    = (u16*)alloc((size_t)2048 * 128 * 2);
    u16* WhhB    = (u16*)alloc((size_t)2048 * 512 * 2);
    u16* WattnT  = (u16*)alloc((size_t)1024 * 512 * 2);
    u16* WembB   = (u16*)alloc((size_t)NVP * 128 * 2);
    u16* embB    = (u16*)alloc((size_t)NR * 128 * 2);
    u16* hdB     = (u16*)alloc((size_t)NR * 512 * 2);
    u16* hX      = (u16*)alloc((size_t)2 * 16384);          // [2][16][16][32] bf16
    float* preGI = (float*)alloc((size_t)NR * 2048 * 4);
    float* hd    = (float*)alloc((size_t)NR * 512 * 4);
    float* q     = (float*)alloc((size_t)NR * 1024 * 4);
    float* p_sw  = (float*)alloc(NR * 4);
    float* copys = (float*)alloc(NR * 4);
    float* lt    = (float*)alloc(NR * 4);
    float* terms = (float*)alloc(NR * 4);
    float* pmax  = (float*)alloc((size_t)NCB * NR * 4);
    float* psum  = (float*)alloc((size_t)NCB * NR * 4);
    unsigned* bar = (unsigned*)alloc(1024);

    // attention scratch overlaid into wbuf (wbuf used only after cat_k)
    u16* h_eB = wbuf;                      // 16*448*512
    u16* h_eT = h_eB + (size_t)16 * 448 * 512;
    u16* qeB  = h_eT + (size_t)16 * 448 * 512;  // 16*64*512
    u16* qdB  = qeB + (size_t)16 * 64 * 512;
    u16* hdUB = qdB + (size_t)16 * 64 * 512;
    u16* hdT  = hdUB + (size_t)16 * 64 * 512;
    u16* PeB  = hdT + (size_t)16 * 64 * 512;    // 16*64*448
    u16* PdB  = PeB + (size_t)16 * 64 * 448;    // 16*64*64
    float* Se = (float*)(PdB + (size_t)16 * 64 * 64);   // 16*64*448 f32
    float* Sd = Se + (size_t)16 * 64 * 448;             // 16*64*64
    float* ce2 = Sd + (size_t)16 * 64 * 64;             // 16*64*512
    float* cd2 = ce2 + (size_t)16 * 64 * 512;           // 16*64*512

    // fused prep (all weight conversions + transposes + gather + hX init)
    fused_prep_k<<<dim3((P_N6 + 255) / 256), 256, 0, stream>>>(
        W_ih, W_hh, W_emb, W_ae, W_ad, W_proj, tgt, h0,
        WihB, WhhB, WembB, WattnT, WprojT, embB, hX);
    prep_he_k<<<dim3(7, 16), 256, 0, stream>>>(h_e, h_eB, h_eT);

    // preGI = emb @ W_ih^T + b_ih + b_hh
    gemm64_k<<<dim3(2048 / 64, NR / 64), 256, 0, stream>>>(embB, WihB, 128, 2048, preGI, b_ih, b_hh);

    // LSTM: 60 steps, 16-block persistent, IC-coherent exchange
    hipMemsetAsync(bar, 0, 1024, stream);
    lstm_all<<<dim3(16), 256, 0, stream>>>(WhhB, hX, preGI, c0, hd, hdB, bar);

    // q = hd @ [W_attn_e | W_attn_d]
    gemm64_k<<<dim3(1024 / 64, NR / 64), 256, 0, stream>>>(hdB, WattnT, 512, 1024, q, nullptr, nullptr);
    qprep_k<<<dim3(64, 16), 256, 0, stream>>>(q, qeB, qdB);
    prep_hd_k<<<dim3(16), 256, 0, stream>>>(hd, hdUB, hdT);

    // scores
    gemm_b_k<<<dim3(7, 1, 16), 256, 0, stream>>>(qeB, 64 * 512, h_eB, 448 * 512, 512, Se, 64 * 448, 448);
    gemm_b_k<<<dim3(1, 1, 16), 256, 0, stream>>>(qdB, 64 * 512, hdUB, 64 * 512, 512, Sd, 64 * 64, 64);
    softmax_ed_k<<<dim3(480), 256, 0, stream>>>(Se, algn, PeB, copys, Sd, PdB);
    // PV
    gemm_b_k<<<dim3(8, 1, 16), 256, 0, stream>>>(PeB, 64 * 448, h_eT, 512 * 448, 448, ce2, 64 * 512, 512);
    gemm_b_k<<<dim3(8, 1, 16), 256, 0, stream>>>(PdB, 64 * 64, hdT, 512 * 64, 64, cd2, 64 * 512, 512);

    cat_k<<<dim3(1024), 256, 0, stream>>>(hd, ce2, cd2, W_u, b_u, catB, p_sw);

    // chunked: W_out chunk = tanh(W_emb @ W_proj), then cat @ chunk^T with streaming LSE + targ capture
    const int vc0s[4] = {0, 12800, 25600, 38400};
    const int nccs[4] = {12800, 12800, 12800, 11904};
    for (int c = 0; c < 4; c++) {
        gemm128_k<1><<<dim3(1536 / 128, nccs[c] / 128), 256, 0, stream>>>(
            WembB + (size_t)vc0s[c] * 128, WprojT, 128, wbuf, 1536,
            nullptr, nullptr, nullptr, 0, nullptr, nullptr);
        gemm128_k<2><<<dim3(nccs[c] / 128, 1024 / 128), 256, 0, stream>>>(
            catB, wbuf, 1536, nullptr, 0, b_out, pmax, psum, vc0s[c], tgt, lt);
    }

    rowred_k<<<dim3(240), 256, 0, stream>>>(pmax, psum, lt, p_sw, copys, tgt, terms);
    final_k<<<dim3(1), 256, 0, stream>>>(terms, (float*)d_out);
}

// Round 9
// 550.866 us; speedup vs baseline: 1.8930x; 1.3890x over previous
//
#include <hip/hip_runtime.h>

typedef unsigned short u16;
typedef __attribute__((ext_vector_type(8))) short bf16x8;
typedef __attribute__((ext_vector_type(4))) float f32x4;
typedef __attribute__((ext_vector_type(4))) unsigned u32x4;

#define NV 50257
#define NVP 50304
#define NR 960          // 60*16 rows
#define NCB 786         // 50304/64 col blocks

__device__ __forceinline__ u16 f2b(float x) {
    union { float f; unsigned u; } v; v.f = x;
    unsigned r = v.u + 0x7FFFu + ((v.u >> 16) & 1u);
    return (u16)(r >> 16);
}
__device__ __forceinline__ ushort4 f2b4(float4 f) {
    ushort4 u; u.x = f2b(f.x); u.y = f2b(f.y); u.z = f2b(f.z); u.w = f2b(f.w);
    return u;
}
__device__ __forceinline__ float b2f(u16 h) {
    union { unsigned u; float f; } v; v.u = ((unsigned)h) << 16;
    return v.f;
}
__device__ __forceinline__ float sigm(float x) { return 1.f / (1.f + __expf(-x)); }

__device__ __forceinline__ void gload16(const u16* g, u16* l) {
    __builtin_amdgcn_global_load_lds((const __attribute__((address_space(1))) void*)g,
                                     (__attribute__((address_space(3))) void*)l, 16, 0, 0);
}

// ---- cross-XCD coherent (L2-bypass, Infinity-Cache coherence point) ops ----
// KNOWN-GOOD (round 5): works regardless of block->XCD placement.
__device__ __forceinline__ u32x4 cload16_async(const void* p) {
    u32x4 r;
    asm volatile("global_load_dwordx4 %0, %1, off sc0 sc1" : "=v"(r) : "v"(p) : "memory");
    return r;
}
__device__ __forceinline__ unsigned cload4(const void* p) {
    unsigned r;
    asm volatile("global_load_dword %0, %1, off sc0 sc1\n\ts_waitcnt vmcnt(0)"
                 : "=v"(r) : "v"(p) : "memory");
    return r;
}
__device__ __forceinline__ void cstore4(void* p, unsigned v) {
    asm volatile("global_store_dword %0, %1, off sc0 sc1" :: "v"(p), "v"(v) : "memory");
}

// ---------------- fused prep ----------------
#define P_N0 65536                    // WihB  (x4)
#define P_N1 (P_N0 + 262144)          // WhhB  (x4)
#define P_N2 (P_N1 + 1609728)         // WembB pad (x4)
#define P_N3 (P_N2 + 524288)          // WattnT (scalar transpose)
#define P_N4 (P_N3 + 196608)          // WprojT (scalar transpose)
#define P_N5 (P_N4 + 30720)           // embB gather (x4)
#define P_N6 (P_N5 + 8192)            // hX init (scalar)
#define P_N7 (P_N6 + 16384)           // hdUB tail zero (dwords)
#define P_N8 (P_N7 + 16384)           // qeB tail zero
#define P_N9 (P_N8 + 16384)           // qdB tail zero
__global__ __launch_bounds__(256) void fused_prep_k(
    const float* __restrict__ W_ih, const float* __restrict__ W_hh,
    const float* __restrict__ W_emb, const float* __restrict__ We,
    const float* __restrict__ Wd, const float* __restrict__ Wp,
    const int* __restrict__ tgt, const float* __restrict__ h0,
    u16* __restrict__ WihB, u16* __restrict__ WhhB, u16* __restrict__ WembB,
    u16* __restrict__ WattnT, u16* __restrict__ WprojT, u16* __restrict__ embB,
    u16* __restrict__ hX, u16* __restrict__ hdUB, u16* __restrict__ qeB,
    u16* __restrict__ qdB)
{
    int i = blockIdx.x * 256 + threadIdx.x;
    if (i < P_N0) {
        ((ushort4*)WihB)[i] = f2b4(((const float4*)W_ih)[i]);
    } else if (i < P_N1) {
        i -= P_N0;
        ((ushort4*)WhhB)[i] = f2b4(((const float4*)W_hh)[i]);
    } else if (i < P_N2) {
        i -= P_N1;
        int e0 = i * 4;
        float4 f;
        if (e0 + 3 < NV * 128) f = ((const float4*)W_emb)[i];
        else {
            f.x = (e0 + 0 < NV * 128) ? W_emb[e0 + 0] : 0.f;
            f.y = (e0 + 1 < NV * 128) ? W_emb[e0 + 1] : 0.f;
            f.z = (e0 + 2 < NV * 128) ? W_emb[e0 + 2] : 0.f;
            f.w = (e0 + 3 < NV * 128) ? W_emb[e0 + 3] : 0.f;
        }
        ((ushort4*)WembB)[i] = f2b4(f);
    } else if (i < P_N3) {
        i -= P_N2;
        int n = i >> 9, k = i & 511;
        float v = (n < 512) ? We[k * 512 + n] : Wd[k * 512 + (n - 512)];
        WattnT[i] = f2b(v);
    } else if (i < P_N4) {
        i -= P_N3;
        int k = i >> 7, e = i & 127;
        WprojT[i] = f2b(Wp[e * 1536 + k]);
    } else if (i < P_N5) {
        i -= P_N4;
        int r = i >> 5, e = (i & 31) * 4;
        float4 f = *(const float4*)&W_emb[(size_t)tgt[r] * 128 + e];
        ((ushort4*)embB)[i] = f2b4(f);
    } else if (i < P_N6) {
        i -= P_N5;
        int b = i >> 9, d = i & 511;
        int blk = d >> 5, dl = d & 31;
        hX[blk * 512 + b * 32 + dl] = f2b(h0[i]);
    } else if (i < P_N7) {
        int j = i - P_N6;
        int b = j >> 10, rem = j & 1023;
        int t = 60 + (rem >> 8), dpair = rem & 255;
        ((unsigned*)hdUB)[((b * 64 + t) << 8) + dpair] = 0;
    } else if (i < P_N8) {
        int j = i - P_N7;
        int b = j >> 10, rem = j & 1023;
        int t = 60 + (rem >> 8), dpair = rem & 255;
        ((unsigned*)qeB)[((b * 64 + t) << 8) + dpair] = 0;
    } else if (i < P_N9) {
        int j = i - P_N8;
        int b = j >> 10, rem = j & 1023;
        int t = 60 + (rem >> 8), dpair = rem & 255;
        ((unsigned*)qdB)[((b * 64 + t) << 8) + dpair] = 0;
    }
}

// h_e [s][b][512] f32 -> h_eB [b][448][512] bf16 (pad s zero), h_eT [b][512][448] bf16
__global__ __launch_bounds__(256) void prep_he_k(const float* __restrict__ h_e,
                                                 u16* __restrict__ h_eB, u16* __restrict__ h_eT) {
    __shared__ u16 tile[64][68];
    const int st = blockIdx.x, b = blockIdx.y, tid = threadIdx.x;
    for (int dc = 0; dc < 8; dc++) {
        const int d0 = dc * 64;
#pragma unroll
        for (int k = 0; k < 4; k++) {
            int o = k * 256 + tid;
            int si = o >> 4, d4 = (o & 15) * 4;
            int s = st * 64 + si;
            float4 f = make_float4(0.f, 0.f, 0.f, 0.f);
            if (s < 400) f = *(const float4*)&h_e[((size_t)s * 16 + b) * 512 + d0 + d4];
            tile[si][d4 + 0] = f2b(f.x); tile[si][d4 + 1] = f2b(f.y);
            tile[si][d4 + 2] = f2b(f.z); tile[si][d4 + 3] = f2b(f.w);
        }
        __syncthreads();
#pragma unroll
        for (int k = 0; k < 4; k++) {
            int o = k * 256 + tid;
            int si = o >> 4, d4 = (o & 15) * 4;
            ushort4 u; u.x = tile[si][d4]; u.y = tile[si][d4 + 1]; u.z = tile[si][d4 + 2]; u.w = tile[si][d4 + 3];
            *(ushort4*)&h_eB[((size_t)b * 448 + st * 64 + si) * 512 + d0 + d4] = u;
        }
#pragma unroll
        for (int k = 0; k < 4; k++) {
            int o = k * 256 + tid;
            int di = o >> 4, s4 = (o & 15) * 4;
            ushort4 u; u.x = tile[s4][di]; u.y = tile[s4 + 1][di]; u.z = tile[s4 + 2][di]; u.w = tile[s4 + 3][di];
            *(ushort4*)&h_eT[((size_t)b * 512 + d0 + di) * 448 + st * 64 + s4] = u;
        }
        __syncthreads();
    }
}

// hdB [(u*16+b)*512] bf16 -> hdT [b][512][64] bf16 (pad u zero)
__global__ __launch_bounds__(256) void prep_hd_k(const u16* __restrict__ hdB,
                                                 u16* __restrict__ hdT) {
    __shared__ u16 tile[64][68];
    const int b = blockIdx.x, tid = threadIdx.x;
    for (int dc = 0; dc < 8; dc++) {
        const int d0 = dc * 64;
#pragma unroll
        for (int k = 0; k < 4; k++) {
            int o = k * 256 + tid;
            int ui = o >> 4, d4 = (o & 15) * 4;
            ushort4 v = make_ushort4(0, 0, 0, 0);
            if (ui < 60) v = *(const ushort4*)&hdB[((size_t)ui * 16 + b) * 512 + d0 + d4];
            tile[ui][d4 + 0] = v.x; tile[ui][d4 + 1] = v.y;
            tile[ui][d4 + 2] = v.z; tile[ui][d4 + 3] = v.w;
        }
        __syncthreads();
#pragma unroll
        for (int k = 0; k < 4; k++) {
            int o = k * 256 + tid;
            int di = o >> 4, u4 = (o & 15) * 4;
            ushort4 u; u.x = tile[u4][di]; u.y = tile[u4 + 1][di]; u.z = tile[u4 + 2][di]; u.w = tile[u4 + 3][di];
            *(ushort4*)&hdT[((size_t)b * 512 + d0 + di) * 64 + u4] = u;
        }
        __syncthreads();
    }
}

// ---------------- 64x64 bf16 MFMA GEMM, f32 out ----------------
__global__ __launch_bounds__(256) void gemm64_k(
    const u16* __restrict__ A, const u16* __restrict__ Bm,
    int K, int ldC, float* __restrict__ outF,
    const float* __restrict__ bias1, const float* __restrict__ bias2)
{
    __shared__ u16 Al[64 * 40];
    __shared__ u16 Bl[64 * 40];
    const int tid = threadIdx.x;
    const int wv = tid >> 6, ln = tid & 63;
    const int bn = blockIdx.x, bm = blockIdx.y;
    const int srow = tid >> 2;
    const int skc = (tid & 3) * 8;
    const size_t aoff = (size_t)(bm * 64 + srow) * K + skc;
    const size_t boff = (size_t)(bn * 64 + srow) * K + skc;
    f32x4 acc[4];
#pragma unroll
    for (int t = 0; t < 4; t++) acc[t] = (f32x4){0.f, 0.f, 0.f, 0.f};
    const int fra = (wv * 16 + (ln & 15)) * 40 + (ln >> 4) * 8;
    for (int kb = 0; kb < K; kb += 32) {
        *(bf16x8*)&Al[srow * 40 + skc] = *(const bf16x8*)&A[aoff + kb];
        *(bf16x8*)&Bl[srow * 40 + skc] = *(const bf16x8*)&Bm[boff + kb];
        __syncthreads();
        bf16x8 af = *(const bf16x8*)&Al[fra];
#pragma unroll
        for (int t = 0; t < 4; t++) {
            bf16x8 bfr = *(const bf16x8*)&Bl[(t * 16 + (ln & 15)) * 40 + (ln >> 4) * 8];
            acc[t] = __builtin_amdgcn_mfma_f32_16x16x32_bf16(af, bfr, acc[t], 0, 0, 0);
        }
        __syncthreads();
    }
    const int rl = wv * 16 + (ln >> 4) * 4;
    const int cl = (ln & 15);
#pragma unroll
    for (int t = 0; t < 4; t++) {
        int col = bn * 64 + t * 16 + cl;
        float bv = 0.f;
        if (bias1) bv += bias1[col];
        if (bias2) bv += bias2[col];
#pragma unroll
        for (int r = 0; r < 4; r++)
            outF[(size_t)(bm * 64 + rl + r) * ldC + col] = acc[t][r] + bv;
    }
}

// ---------------- q GEMM with bf16 split epilogue (qeB | qdB) ----------------
__global__ __launch_bounds__(256) void gemm64q_k(
    const u16* __restrict__ A, const u16* __restrict__ Bm,
    u16* __restrict__ qeB, u16* __restrict__ qdB)
{
    __shared__ u16 Al[64 * 40];
    __shared__ u16 Bl[64 * 40];
    const int tid = threadIdx.x;
    const int wv = tid >> 6, ln = tid & 63;
    const int bn = blockIdx.x, bm = blockIdx.y;
    const int srow = tid >> 2;
    const int skc = (tid & 3) * 8;
    const size_t aoff = (size_t)(bm * 64 + srow) * 512 + skc;
    const size_t boff = (size_t)(bn * 64 + srow) * 512 + skc;
    f32x4 acc[4];
#pragma unroll
    for (int t = 0; t < 4; t++) acc[t] = (f32x4){0.f, 0.f, 0.f, 0.f};
    const int fra = (wv * 16 + (ln & 15)) * 40 + (ln >> 4) * 8;
    for (int kb = 0; kb < 512; kb += 32) {
        *(bf16x8*)&Al[srow * 40 + skc] = *(const bf16x8*)&A[aoff + kb];
        *(bf16x8*)&Bl[srow * 40 + skc] = *(const bf16x8*)&Bm[boff + kb];
        __syncthreads();
        bf16x8 af = *(const bf16x8*)&Al[fra];
#pragma unroll
        for (int t = 0; t < 4; t++) {
            bf16x8 bfr = *(const bf16x8*)&Bl[(t * 16 + (ln & 15)) * 40 + (ln >> 4) * 8];
            acc[t] = __builtin_amdgcn_mfma_f32_16x16x32_bf16(af, bfr, acc[t], 0, 0, 0);
        }
        __syncthreads();
    }
    const int rl = wv * 16 + (ln >> 4) * 4;
    const int cl = (ln & 15);
#pragma unroll
    for (int t = 0; t < 4; t++) {
        int col = bn * 64 + t * 16 + cl;
#pragma unroll
        for (int r = 0; r < 4; r++) {
            int row = bm * 64 + rl + r;
            int tt = row >> 4, bb = row & 15;
            u16 v = f2b(acc[t][r]);
            if (col < 512) qeB[((size_t)bb * 64 + tt) * 512 + col] = v;
            else           qdB[((size_t)bb * 64 + tt) * 512 + (col - 512)] = v;
        }
    }
}

// ---------------- batched 64-wide A*B^T GEMM (M=64), f32 out ----------------
__global__ __launch_bounds__(256) void gemm_b_k(
    const u16* __restrict__ A, long sA,
    const u16* __restrict__ Bm, long sB, int K,
    float* __restrict__ C, long sC, int ldC)
{
    __shared__ u16 Al[64 * 40];
    __shared__ u16 Bl[64 * 40];
    const int tid = threadIdx.x;
    const int wv = tid >> 6, ln = tid & 63;
    const int bn = blockIdx.x, bz = blockIdx.z;
    A += (size_t)bz * sA; Bm += (size_t)bz * sB; C += (size_t)bz * sC;
    const int srow = tid >> 2;
    const int skc = (tid & 3) * 8;
    const size_t aoff = (size_t)srow * K + skc;
    const size_t boff = (size_t)(bn * 64 + srow) * K + skc;
    f32x4 acc[4];
#pragma unroll
    for (int t = 0; t < 4; t++) acc[t] = (f32x4){0.f, 0.f, 0.f, 0.f};
    const int fra = (wv * 16 + (ln & 15)) * 40 + (ln >> 4) * 8;
    for (int kb = 0; kb < K; kb += 32) {
        *(bf16x8*)&Al[srow * 40 + skc] = *(const bf16x8*)&A[aoff + kb];
        *(bf16x8*)&Bl[srow * 40 + skc] = *(const bf16x8*)&Bm[boff + kb];
        __syncthreads();
        bf16x8 af = *(const bf16x8*)&Al[fra];
#pragma unroll
        for (int t = 0; t < 4; t++) {
            bf16x8 bfr = *(const bf16x8*)&Bl[(t * 16 + (ln & 15)) * 40 + (ln >> 4) * 8];
            acc[t] = __builtin_amdgcn_mfma_f32_16x16x32_bf16(af, bfr, acc[t], 0, 0, 0);
        }
        __syncthreads();
    }
    const int rl = wv * 16 + (ln >> 4) * 4;
    const int cl = (ln & 15);
#pragma unroll
    for (int t = 0; t < 4; t++) {
        int col = bn * 64 + t * 16 + cl;
#pragma unroll
        for (int r = 0; r < 4; r++)
            C[(size_t)(rl + r) * ldC + col] = acc[t][r];
    }
}

// ---------------- MODE1 tile: out[vrow0..+128][bn*128..+128] = tanh(WembB @ WprojT^T) ----------------
__device__ __forceinline__ void mode1_tile(
    const u16* __restrict__ A, const u16* __restrict__ Bm, u16* __restrict__ out,
    int vrow0, int bn, int tid, u16* Al, u16* Bl)
{
    const int w = tid >> 6, ln = tid & 63;
    const int wr = w >> 1, wc = w & 1;
    const int srow = w * 16 + (ln >> 2);
    const int scol = (ln & 3) * 8;
    const u16* ag = A + (size_t)(vrow0 + srow) * 128 + scol;
    const u16* bg = Bm + (size_t)(bn * 128 + srow) * 128 + scol;
    u16* la = &Al[w * 16 * 32];
    u16* lb = &Bl[w * 16 * 32];
    f32x4 acc[4][4];
#pragma unroll
    for (int m = 0; m < 4; m++)
#pragma unroll
        for (int n = 0; n < 4; n++) acc[m][n] = (f32x4){0.f, 0.f, 0.f, 0.f};
    const int ra = (wr * 64 + (ln & 15)) * 32 + (ln >> 4) * 8;
    const int rb = (wc * 64 + (ln & 15)) * 32 + (ln >> 4) * 8;
    for (int kb = 0; kb < 128; kb += 32) {
        gload16(ag + kb, la);
        gload16(ag + (size_t)64 * 128 + kb, la + 64 * 32);
        gload16(bg + kb, lb);
        gload16(bg + (size_t)64 * 128 + kb, lb + 64 * 32);
        __syncthreads();
        bf16x8 af[4], bfr[4];
#pragma unroll
        for (int m = 0; m < 4; m++) af[m] = *(const bf16x8*)&Al[ra + m * 16 * 32];
#pragma unroll
        for (int n = 0; n < 4; n++) bfr[n] = *(const bf16x8*)&Bl[rb + n * 16 * 32];
#pragma unroll
        for (int m = 0; m < 4; m++)
#pragma unroll
            for (int n = 0; n < 4; n++)
                acc[m][n] = __builtin_amdgcn_mfma_f32_16x16x32_bf16(af[m], bfr[n], acc[m][n], 0, 0, 0);
        __syncthreads();
    }
    const int cl = ln & 15, rg = ln >> 4;
#pragma unroll
    for (int m = 0; m < 4; m++) {
        int row0 = vrow0 + wr * 64 + m * 16 + rg * 4;
#pragma unroll
        for (int n = 0; n < 4; n++) {
            int col = bn * 128 + wc * 64 + n * 16 + cl;
#pragma unroll
            for (int r = 0; r < 4; r++)
                out[(size_t)(row0 + r) * 1536 + col] = f2b(tanhf(acc[m][n][r]));
        }
    }
}

// path-B standalone MODE1
__global__ __launch_bounds__(256) void gemm128m1_k(
    const u16* __restrict__ A, const u16* __restrict__ Bm, u16* __restrict__ outAbs, int vc0)
{
    __shared__ __align__(16) u16 Al[128 * 32];
    __shared__ __align__(16) u16 Bl[128 * 32];
    mode1_tile(A, Bm, outAbs, vc0 + blockIdx.y * 128, blockIdx.x, threadIdx.x, Al, Bl);
}

// ---------------- MODE2: streaming LSE + targ, XCD-swizzled (gridDim.x == 8 row-tiles) ----------------
__global__ __launch_bounds__(256) void gemm128lse_k(
    const u16* __restrict__ A, const u16* __restrict__ Bm,
    const float* __restrict__ bias,
    float* __restrict__ pmax, float* __restrict__ psum, const int vc0,
    const int* __restrict__ tgt, float* __restrict__ lt)
{
    __shared__ u16 Al[128 * 32];
    __shared__ u16 Bl[128 * 32];
    const int tid = threadIdx.x;
    const int w = tid >> 6, ln = tid & 63;
    const int wr = w >> 1, wc = w & 1;
    // bijective XCD swizzle: per-XCD contiguous chunk, bm-fastest
    const int lid = blockIdx.x + blockIdx.y * 8;
    const int chunk = gridDim.y;           // nwg/8 (gridDim.x==8)
    const int f = (lid & 7) * chunk + (lid >> 3);
    const int bm = f & 7, bn = f >> 3;
    const int K = 1536;
    const int srow = w * 16 + (ln >> 2);
    const int scol = (ln & 3) * 8;
    const u16* ag = A + (size_t)bm * 128 * K + (size_t)srow * K + scol;
    const u16* bg = Bm + (size_t)bn * 128 * K + (size_t)srow * K + scol;
    u16* la = &Al[w * 16 * 32];
    u16* lb = &Bl[w * 16 * 32];
    f32x4 acc[4][4];
#pragma unroll
    for (int m = 0; m < 4; m++)
#pragma unroll
        for (int n = 0; n < 4; n++) acc[m][n] = (f32x4){0.f, 0.f, 0.f, 0.f};
    const int ra = (wr * 64 + (ln & 15)) * 32 + (ln >> 4) * 8;
    const int rb = (wc * 64 + (ln & 15)) * 32 + (ln >> 4) * 8;

    for (int kb = 0; kb < K; kb += 32) {
        gload16(ag + kb, la);
        gload16(ag + (size_t)64 * K + kb, la + 64 * 32);
        gload16(bg + kb, lb);
        gload16(bg + (size_t)64 * K + kb, lb + 64 * 32);
        __syncthreads();
        bf16x8 af[4], bfr[4];
#pragma unroll
        for (int m = 0; m < 4; m++) af[m] = *(const bf16x8*)&Al[ra + m * 16 * 32];
#pragma unroll
        for (int n = 0; n < 4; n++) bfr[n] = *(const bf16x8*)&Bl[rb + n * 16 * 32];
#pragma unroll
        for (int m = 0; m < 4; m++)
#pragma unroll
            for (int n = 0; n < 4; n++)
                acc[m][n] = __builtin_amdgcn_mfma_f32_16x16x32_bf16(af[m], bfr[n], acc[m][n], 0, 0, 0);
        __syncthreads();
    }

    const int cl = ln & 15, rg = ln >> 4;
    const int cbg = (vc0 >> 6) + bn * 2 + wc;
    float bo[4]; int vg[4];
#pragma unroll
    for (int n = 0; n < 4; n++) {
        vg[n] = vc0 + bn * 128 + wc * 64 + n * 16 + cl;
        bo[n] = (vg[n] < NV) ? bias[vg[n]] : 0.f;
    }
#pragma unroll
    for (int m = 0; m < 4; m++) {
        int row0 = bm * 128 + wr * 64 + m * 16 + rg * 4;
#pragma unroll
        for (int r = 0; r < 4; r++) {
            int row = row0 + r;
            int tv = (row < NR) ? tgt[row] : -1;
            float lg[4]; float mm = -1e30f;
#pragma unroll
            for (int n = 0; n < 4; n++) {
                lg[n] = (vg[n] < NV) ? (acc[m][n][r] + bo[n]) : -1e30f;
                mm = fmaxf(mm, lg[n]);
                if (vg[n] == tv) lt[row] = lg[n];
            }
            mm = fmaxf(mm, __shfl_xor(mm, 1, 64));
            mm = fmaxf(mm, __shfl_xor(mm, 2, 64));
            mm = fmaxf(mm, __shfl_xor(mm, 4, 64));
            mm = fmaxf(mm, __shfl_xor(mm, 8, 64));
            float s = 0.f;
#pragma unroll
            for (int n = 0; n < 4; n++) s += __expf(lg[n] - mm);
            s += __shfl_xor(s, 1, 64); s += __shfl_xor(s, 2, 64);
            s += __shfl_xor(s, 4, 64); s += __shfl_xor(s, 8, 64);
            if (cl == 0 && row < NR) {
                pmax[(size_t)cbg * NR + row] = mm;
                psum[(size_t)cbg * NR + row] = s;
            }
        }
    }
}

// ---------------- fused: LSTM blocks 0..15 (round-5 IC-coherent sync) + MODE1 workers >=16 ----------------
// No placement assumptions: sc0 sc1 sync is valid across XCDs. Workers never wait on LSTM
// (no circular dependency -> deadlock-impossible).
__global__ __launch_bounds__(256) void lstm_fused_k(
    const u16* __restrict__ WhhB, u16* __restrict__ hX,
    const float* __restrict__ preGI, const float* __restrict__ c0,
    u16* __restrict__ hdB, u16* __restrict__ hdUB, unsigned* __restrict__ bar,
    const u16* __restrict__ WembB, const u16* __restrict__ WprojT, u16* __restrict__ wOut)
{
    __shared__ __align__(16) char smem[16384];
    const int tid = threadIdx.x;

    if (blockIdx.x >= 16) {
        // MODE1 worker: tanh(WembB @ WprojT^T) tile
        int bid2 = blockIdx.x - 16;
        int bn = bid2 % 12;
        int vr = (bid2 / 12) * 128;
        mode1_tile(WembB, WprojT, wOut, vr, bn, tid, (u16*)smem, (u16*)(smem + 8192));
        return;
    }

    // ---- LSTM block, role = blockIdx.x, d-range [role*32, role*32+32) ----
    float* gl = (float*)smem;             // [4*32][17]
    const int g = tid >> 6, ln = tid & 63;
    const int role = blockIdx.x;
    bf16x8 aw[2][16];
#pragma unroll
    for (int m = 0; m < 2; m++) {
        const int arow = (g * 512 + role * 32 + m * 16 + (ln & 15)) * 512 + ((ln >> 4) * 8);
#pragma unroll
        for (int kb = 0; kb < 16; kb++) aw[m][kb] = *(const bf16x8*)&WhhB[arow + kb * 32];
    }
    const int b = tid >> 4, dp = tid & 15;
    const int d0 = role * 32 + dp * 2;
    float c_0 = c0[b * 512 + d0];
    float c_1 = c0[b * 512 + d0 + 1];
    const int hoff = (ln & 15) * 64 + (ln >> 4) * 16;

    for (int t = 0; t < 60; t++) {
        const char* hin = (const char*)hX + (size_t)(t & 1) * 16384;
        u32x4 hv[16];
#pragma unroll
        for (int kb = 0; kb < 16; kb++)
            hv[kb] = cload16_async(hin + kb * 1024 + hoff);
        const float* pg = preGI + ((size_t)t * 16 + b) * 2048 + d0;
        float2 p0 = *(const float2*)&pg[0];
        float2 p1 = *(const float2*)&pg[512];
        float2 p2 = *(const float2*)&pg[1024];
        float2 p3 = *(const float2*)&pg[1536];
        asm volatile("" :: "v"(p0.x), "v"(p0.y), "v"(p1.x), "v"(p1.y),
                           "v"(p2.x), "v"(p2.y), "v"(p3.x), "v"(p3.y));
        asm volatile("s_waitcnt vmcnt(0)" ::: "memory");
        __builtin_amdgcn_sched_barrier(0);
        f32x4 acc0 = {0.f, 0.f, 0.f, 0.f}, acc1 = {0.f, 0.f, 0.f, 0.f};
#pragma unroll
        for (int kb = 0; kb < 16; kb++) {
            union { u32x4 u; bf16x8 h; } cv; cv.u = hv[kb];
            acc0 = __builtin_amdgcn_mfma_f32_16x16x32_bf16(aw[0][kb], cv.h, acc0, 0, 0, 0);
            acc1 = __builtin_amdgcn_mfma_f32_16x16x32_bf16(aw[1][kb], cv.h, acc1, 0, 0, 0);
        }
#pragma unroll
        for (int r = 0; r < 4; r++) {
            gl[(g * 32 + (ln >> 4) * 4 + r) * 17 + (ln & 15)] = acc0[r];
            gl[(g * 32 + 16 + (ln >> 4) * 4 + r) * 17 + (ln & 15)] = acc1[r];
        }
        __syncthreads();
        const int dl0 = dp * 2;
        float i0 = gl[(0 * 32 + dl0) * 17 + b] + p0.x;
        float i1 = gl[(0 * 32 + dl0 + 1) * 17 + b] + p0.y;
        float f0 = gl[(1 * 32 + dl0) * 17 + b] + p1.x;
        float f1 = gl[(1 * 32 + dl0 + 1) * 17 + b] + p1.y;
        float g0 = gl[(2 * 32 + dl0) * 17 + b] + p2.x;
        float g1 = gl[(2 * 32 + dl0 + 1) * 17 + b] + p2.y;
        float o0 = gl[(3 * 32 + dl0) * 17 + b] + p3.x;
        float o1 = gl[(3 * 32 + dl0 + 1) * 17 + b] + p3.y;
        c_0 = sigm(f0) * c_0 + sigm(i0) * tanhf(g0);
        c_1 = sigm(f1) * c_1 + sigm(i1) * tanhf(g1);
        float h_0 = sigm(o0) * tanhf(c_0);
        float h_1 = sigm(o1) * tanhf(c_1);
        u16 hb0 = f2b(h_0), hb1 = f2b(h_1);
        unsigned pk = (unsigned)hb0 | ((unsigned)hb1 << 16);
        if (t < 59) {
            char* hout = (char*)hX + (size_t)((t & 1) ^ 1) * 16384;
            cstore4(hout + role * 1024 + b * 64 + dp * 4, pk);
            asm volatile("s_waitcnt vmcnt(0)" ::: "memory");
            __syncthreads();
            if (tid == 0) cstore4(&bar[role * 16], (unsigned)(t + 1));
        }
        // bulk outputs off the critical path
        *(unsigned*)&hdB[(size_t)t * 8192 + b * 512 + d0] = pk;
        *(unsigned*)&hdUB[((size_t)b * 64 + t) * 512 + d0] = pk;
        if (t < 59) {
            const unsigned target = (unsigned)(t + 1);
            while (true) {
                unsigned v = target;
                if (ln < 16) v = cload4(&bar[ln * 16]);
                if (__all(v >= target)) break;
                __builtin_amdgcn_s_sleep(1);
            }
        }
    }
}

// ---------------- fused softmax ----------------
__global__ __launch_bounds__(256) void softmax_ed_k(
    const float* __restrict__ Se, const float* __restrict__ algn,
    u16* __restrict__ PeB, float* __restrict__ copysum,
    const float* __restrict__ Sd, u16* __restrict__ PdB)
{
    const int l = threadIdx.x & 63;
    if (blockIdx.x < 240) {
        const int wid = blockIdx.x * 4 + (threadIdx.x >> 6);
        const int t = wid >> 4, b = wid & 15;
        const float* srow = &Se[((size_t)b * 64 + t) * 448];
        float v[7];
        float m = -1e30f;
#pragma unroll
        for (int i = 0; i < 7; i++) {
            int s = l + i * 64;
            v[i] = (s < 400) ? srow[s] : -1e30f;
            m = fmaxf(m, v[i]);
        }
#pragma unroll
        for (int mk = 1; mk < 64; mk <<= 1) m = fmaxf(m, __shfl_xor(m, mk, 64));
        const float* arow = &algn[((size_t)t * 16 + b) * 400];
        float se = 0.f, ca = 0.f;
#pragma unroll
        for (int i = 0; i < 7; i++) {
            int s = l + i * 64;
            float e = (s < 400) ? __expf(v[i] - m) : 0.f;
            v[i] = e; se += e;
            if (s < 400) ca += e * arow[s];
        }
#pragma unroll
        for (int mk = 1; mk < 64; mk <<= 1) { se += __shfl_xor(se, mk, 64); ca += __shfl_xor(ca, mk, 64); }
        float inv = 1.f / se;
#pragma unroll
        for (int i = 0; i < 7; i++) {
            int s = l + i * 64;
            PeB[((size_t)b * 64 + t) * 448 + s] = f2b(v[i] * inv);
        }
        if (l == 0) copysum[t * 16 + b] = ca * inv;
    } else {
        const int wid = (blockIdx.x - 240) * 4 + (threadIdx.x >> 6);
        const int t = wid >> 4, b = wid & 15;
        float v = Sd[((size_t)b * 64 + t) * 64 + l];
        bool ok = (l <= t) && (l < 60);
        v = ok ? v : -1e30f;
        float m = v;
#pragma unroll
        for (int mk = 1; mk < 64; mk <<= 1) m = fmaxf(m, __shfl_xor(m, mk, 64));
        float e = ok ? __expf(v - m) : 0.f;
        float se = e;
#pragma unroll
        for (int mk = 1; mk < 64; mk <<= 1) se += __shfl_xor(se, mk, 64);
        float p = (t == 0) ? 0.f : e / se;
        PdB[((size_t)b * 64 + t) * 64 + l] = f2b(p);
    }
}

// ---------------- cat assembly + p_switch (reads hdB bf16) ----------------
__global__ __launch_bounds__(256) void cat_k(
    const u16* __restrict__ hdB, const float* __restrict__ ce2, const float* __restrict__ cd2,
    const float* __restrict__ W_u, const float* __restrict__ b_u,
    u16* __restrict__ catB, float* __restrict__ p_switch)
{
    const int r = blockIdx.x, tid = threadIdx.x;
    if (r >= NR) {
        for (int j = tid; j < 1536; j += 256) catB[(size_t)r * 1536 + j] = 0;
        return;
    }
    const int t = r >> 4, b = r & 15;
    float partial = 0.f;
    for (int j = tid; j < 1536; j += 256) {
        u16 uv; float v;
        if (j < 512) { uv = hdB[(size_t)r * 512 + j]; v = b2f(uv); }
        else if (j < 1024) { v = ce2[((size_t)b * 64 + t) * 512 + (j - 512)]; uv = f2b(v); }
        else { v = cd2[((size_t)b * 64 + t) * 512 + (j - 1024)]; uv = f2b(v); }
        catB[(size_t)r * 1536 + j] = uv;
        partial += v * W_u[j];
    }
#pragma unroll
    for (int mk = 1; mk < 64; mk <<= 1) partial += __shfl_xor(partial, mk, 64);
    __shared__ float red[4];
    if ((tid & 63) == 0) red[tid >> 6] = partial;
    __syncthreads();
    if (tid == 0) {
        float u = red[0] + red[1] + red[2] + red[3] + b_u[0];
        p_switch[r] = 1.f / (1.f + __expf(-u));
    }
}

// ---------------- per-row LSE combine (wave per row) ----------------
__global__ __launch_bounds__(256) void rowred_k(
    const float* __restrict__ pmax, const float* __restrict__ psum,
    const float* __restrict__ lt, const float* __restrict__ p_switch,
    const float* __restrict__ copysum, const int* __restrict__ tgt,
    float* __restrict__ terms)
{
    const int r = blockIdx.x * 4 + (threadIdx.x >> 6);
    const int l = threadIdx.x & 63;
    float m = -1e30f, s = 0.f;
    for (int cb = l; cb < NCB; cb += 64) {
        float me = pmax[(size_t)cb * NR + r];
        float se = psum[(size_t)cb * NR + r];
        float M2 = fmaxf(m, me);
        s = s * __expf(m - M2) + se * __expf(me - M2);
        m = M2;
    }
#pragma unroll
    for (int mk = 1; mk < 64; mk <<= 1) {
        float mo = __shfl_xor(m, mk, 64);
        float so = __shfl_xor(s, mk, 64);
        float M2 = fmaxf(m, mo);
        s = s * __expf(m - M2) + so * __expf(mo - M2);
        m = M2;
    }
    if (l == 0) {
        float ps = p_switch[r];
        float tg = (1.f - ps) * __expf(lt[r] - m) / s;
        float tc = ps * copysum[r];
        terms[r] = (tgt[r] != 0) ? -logf(tg + tc + 2e-12f) : 0.f;
    }
}

__global__ __launch_bounds__(256) void final_k(const float* __restrict__ terms, float* __restrict__ out)
{
    const int tid = threadIdx.x;
    float p = 0.f;
    for (int i = tid; i < NR; i += 256) p += terms[i];
#pragma unroll
    for (int mk = 1; mk < 64; mk <<= 1) p += __shfl_xor(p, mk, 64);
    __shared__ float red[4];
    if ((tid & 63) == 0) red[tid >> 6] = p;
    __syncthreads();
    if (tid == 0) out[0] = red[0] + red[1] + red[2] + red[3];
}

// ---------------- host launch ----------------
extern "C" void kernel_launch(void* const* d_in, const int* in_sizes, int n_in,
                              void* d_out, int out_size, void* d_ws, size_t ws_size,
                              hipStream_t stream)
{
    const int*   tgt    = (const int*)d_in[0];
    const float* algn   = (const float*)d_in[2];
    const float* h_e    = (const float*)d_in[3];
    const float* h0     = (const float*)d_in[4];
    const float* c0     = (const float*)d_in[5];
    const float* W_emb  = (const float*)d_in[6];
    const float* W_ih   = (const float*)d_in[7];
    const float* W_hh   = (const float*)d_in[8];
    const float* b_ih   = (const float*)d_in[9];
    const float* b_hh   = (const float*)d_in[10];
    const float* W_ae   = (const float*)d_in[11];
    const float* W_ad   = (const float*)d_in[12];
    const float* W_proj = (const float*)d_in[13];
    const float* W_u    = (const float*)d_in[14];
    const float* b_u    = (const float*)d_in[15];
    const float* b_out  = (const float*)d_in[16];
    (void)in_sizes; (void)n_in; (void)out_size;

    const bool big = ws_size >= ((size_t)250 << 20);

    char* ws = (char*)d_ws;
    size_t off = 0;
    auto alloc = [&](size_t bytes) -> char* {
        char* p = ws + off;
        off += (bytes + 255) & ~(size_t)255;
        return p;
    };
    u16* wbuf    = (u16*)alloc(big ? (size_t)NVP * 1536 * 2 : (size_t)12800 * 1536 * 2);
    u16* catB    = (u16*)alloc((size_t)1024 * 1536 * 2);
    u16* WprojT  = (u16*)alloc((size_t)1536 * 128 * 2);
    u16* WihB    = (u16*)alloc((size_t)2048 * 128 * 2);
    u16* WhhB    = (u16*)alloc((size_t)2048 * 512 * 2);
    u16* WattnT  = (u16*)alloc((size_t)1024 * 512 * 2);
    u16* WembB   = (u16*)alloc((size_t)NVP * 128 * 2);
    u16* embB    = (u16*)alloc((size_t)NR * 128 * 2);
    u16* hdB     = (u16*)alloc((size_t)NR * 512 * 2);
    u16* hX      = (u16*)alloc((size_t)2 * 16384);
    float* preGI = (float*)alloc((size_t)NR * 2048 * 4);
    float* p_sw  = (float*)alloc(NR * 4);
    float* copys = (float*)alloc(NR * 4);
    float* lt    = (float*)alloc(NR * 4);
    float* terms = (float*)alloc(NR * 4);
    float* pmax  = (float*)alloc((size_t)NCB * NR * 4);
    float* psum  = (float*)alloc((size_t)NCB * NR * 4);
    unsigned* bar = (unsigned*)alloc(4096);

    // attention scratch: separate region in big path, overlays wbuf otherwise
    size_t attnBytes = ((size_t)16 * 448 * 512 * 2) * 2 + ((size_t)16 * 64 * 512 * 2) * 4
                     + (size_t)16 * 64 * 448 * 2 + (size_t)16 * 64 * 64 * 2
                     + (size_t)16 * 64 * 448 * 4 + (size_t)16 * 64 * 64 * 4
                     + ((size_t)16 * 64 * 512 * 4) * 2 + 4096;
    char* ab = big ? alloc(attnBytes) : (char*)wbuf;
    u16* h_eB = (u16*)ab;
    u16* h_eT = h_eB + (size_t)16 * 448 * 512;
    u16* qeB  = h_eT + (size_t)16 * 448 * 512;
    u16* qdB  = qeB + (size_t)16 * 64 * 512;
    u16* hdUB = qdB + (size_t)16 * 64 * 512;
    u16* hdT  = hdUB + (size_t)16 * 64 * 512;
    u16* PeB  = hdT + (size_t)16 * 64 * 512;
    u16* PdB  = PeB + (size_t)16 * 64 * 448;
    float* Se = (float*)(PdB + (size_t)16 * 64 * 64);
    float* Sd = Se + (size_t)16 * 64 * 448;
    float* ce2 = Sd + (size_t)16 * 64 * 64;
    float* cd2 = ce2 + (size_t)16 * 64 * 512;

    // prep
    fused_prep_k<<<dim3((P_N9 + 255) / 256), 256, 0, stream>>>(
        W_ih, W_hh, W_emb, W_ae, W_ad, W_proj, tgt, h0,
        WihB, WhhB, WembB, WattnT, WprojT, embB, hX, hdUB, qeB, qdB);
    prep_he_k<<<dim3(7, 16), 256, 0, stream>>>(h_e, h_eB, h_eT);

    // preGI = emb @ W_ih^T + b_ih + b_hh
    gemm64_k<<<dim3(2048 / 64, NR / 64), 256, 0, stream>>>(embB, WihB, 128, 2048, preGI, b_ih, b_hh);

    // LSTM (round-5 IC-coherent sync) + concurrent MODE1 workers (big path)
    hipMemsetAsync(bar, 0, 4096, stream);
    {
        int nblocks = 16 + (big ? 4716 : 0);   // 4716 = (50304/128)*12
        lstm_fused_k<<<dim3(nblocks), 256, 0, stream>>>(
            WhhB, hX, preGI, c0, hdB, hdUB, bar, WembB, WprojT, wbuf);
    }

    // q = hd @ [W_attn_e | W_attn_d] -> qeB/qdB bf16 directly
    gemm64q_k<<<dim3(16, 15), 256, 0, stream>>>(hdB, WattnT, qeB, qdB);
    prep_hd_k<<<dim3(16), 256, 0, stream>>>(hdB, hdT);

    // scores
    gemm_b_k<<<dim3(7, 1, 16), 256, 0, stream>>>(qeB, 64 * 512, h_eB, 448 * 512, 512, Se, 64 * 448, 448);
    gemm_b_k<<<dim3(1, 1, 16), 256, 0, stream>>>(qdB, 64 * 512, hdUB, 64 * 512, 512, Sd, 64 * 64, 64);
    softmax_ed_k<<<dim3(480), 256, 0, stream>>>(Se, algn, PeB, copys, Sd, PdB);
    // PV
    gemm_b_k<<<dim3(8, 1, 16), 256, 0, stream>>>(PeB, 64 * 448, h_eT, 512 * 448, 448, ce2, 64 * 512, 512);
    gemm_b_k<<<dim3(8, 1, 16), 256, 0, stream>>>(PdB, 64 * 64, hdT, 512 * 64, 64, cd2, 64 * 512, 512);

    cat_k<<<dim3(1024), 256, 0, stream>>>(hdB, ce2, cd2, W_u, b_u, catB, p_sw);

    if (big) {
        // single MODE2 sweep over full W_out (already computed under the LSTM)
        gemm128lse_k<<<dim3(8, 393), 256, 0, stream>>>(catB, wbuf, b_out, pmax, psum, 0, tgt, lt);
    } else {
        const int vc0s[4] = {0, 12800, 25600, 38400};
        const int nccs[4] = {12800, 12800, 12800, 11904};
        for (int c = 0; c < 4; c++) {
            gemm128m1_k<<<dim3(12, nccs[c] / 128), 256, 0, stream>>>(
                WembB, WprojT, wbuf - (size_t)vc0s[c] * 1536, vc0s[c]);
            gemm128lse_k<<<dim3(8, nccs[c] / 128), 256, 0, stream>>>(
                catB, wbuf, b_out, pmax, psum, vc0s[c], tgt, lt);
        }
    }

    rowred_k<<<dim3(240), 256, 0, stream>>>(pmax, psum, lt, p_sw, copys, tgt, terms);
    final_k<<<dim3(1), 256, 0, stream>>>(terms, (float*)d_out);
}